// Round 3
// baseline (1084.211 us; speedup 1.0000x reference)
//
#include <hip/hip_runtime.h>

#define HIDD 1024
#define NHH  16
#define HDD  64
#define BBB  2
#define SSS  2048
#define BS   (BBB * SSS)   // 4096

#define LSX 68   // LDS row stride in f32 (64 + 4 pad; 272 B, 16B-aligned)

// =====================================================================================
// ANCHOR ROUND: everything in plain f32 VALU. No MFMA, no bf16, no layout tricks.
// Purpose: bisect the persistent ~8e-3 error (semantic vs MFMA-machinery).
// =====================================================================================

// ---------------- per-head Q/K/V projection, plain f32 ----------------
// x: [BS][HID] f32 ; wq/wk/wv: [NH][d][e] f32 (native layout, no transpose)
// Q,K,V: [B*NH][S][HD] f32 (all row-major)
__global__ __launch_bounds__(256) void k_proj_f32(const float* __restrict__ x,
                                                  const float* __restrict__ wq,
                                                  const float* __restrict__ wk,
                                                  const float* __restrict__ wv,
                                                  float* __restrict__ Q,
                                                  float* __restrict__ K,
                                                  float* __restrict__ V) {
    const int n  = blockIdx.y;
    const int R0 = blockIdx.x * 64;
    const int tid = threadIdx.x;
    const int row = tid >> 2, g = tid & 3;    // 64 rows x 4 col-groups of 16

    __shared__ float xs[64 * LSX];
    __shared__ float ws[64 * LSX];

    // stage x head-slice [64 rows][64 d]
    for (int c = tid; c < 1024; c += 256) {
        int r = c >> 4, c4 = (c & 15) * 4;
        *(float4*)&xs[r * LSX + c4] =
            *(const float4*)(x + (size_t)(R0 + r) * HIDD + n * HDD + c4);
    }

    const float* wmats[3] = { wq, wk, wv };
    const int gr = R0 + row;
    const int b = gr >> 11, s = gr & 2047;
    const size_t bn = (size_t)(b * NHH + n);

    for (int mat = 0; mat < 3; ++mat) {
        __syncthreads();
        // stage weight head-slice [d][e] (native layout)
        for (int c = tid; c < 1024; c += 256) {
            int r = c >> 4, c4 = (c & 15) * 4;
            *(float4*)&ws[r * LSX + c4] =
                *(const float4*)(wmats[mat] + (size_t)n * HDD * HDD + r * HDD + c4);
        }
        __syncthreads();

        float acc[16];
#pragma unroll
        for (int c = 0; c < 16; ++c) acc[c] = 0.f;
        for (int d = 0; d < 64; ++d) {
            float xv = xs[row * LSX + d];
#pragma unroll
            for (int c = 0; c < 16; ++c) acc[c] += xv * ws[d * LSX + 16 * g + c];
        }

        float* dst = (mat == 0) ? Q : (mat == 1) ? K : V;
        size_t base = (bn * SSS + s) * HDD + 16 * g;
#pragma unroll
        for (int j = 0; j < 4; ++j)
            *(float4*)(dst + base + 4 * j) = *(float4*)&acc[4 * j];
    }
}

// ---------------- retention, plain f32, + fused GroupNorm ----------------
// Each thread: one q-row, 16 channels. Scores via 4-thread partial dot + shfl.
__global__ __launch_bounds__(256) void k_ret_f32(const float* __restrict__ Q,
                                                 const float* __restrict__ K,
                                                 const float* __restrict__ V,
                                                 const float* __restrict__ gns,
                                                 const float* __restrict__ gnb,
                                                 float* __restrict__ normb) {
    const int qt = (gridDim.x - 1) - blockIdx.x;   // heavy (late) tiles launch first
    const int n = blockIdx.y, b = blockIdx.z;
    const int tid = threadIdx.x;
    const int rloc = tid >> 2, g = tid & 3;
    const int sb = qt * 64;
    const int srow = sb + rloc;

    // gammas exactly like the reference (f64 linspace/exp, cast to f32)
    const double l512 = -6.2383246250395075;   // log(1/512)
    const double l32  = -3.4657359027997265;   // log(1/32)
    double lin = l512 + (double)n * (l32 - l512) / 15.0;
    float gamma = (float)(1.0 - exp(lin));
    float l2g = log2f(gamma);                  // negative
    int dmax = (int)(30.0f / (-l2g)) + 1;      // keep gamma^d >= 2^-30
    int tb_start = (sb > dmax) ? ((sb - dmax) >> 6) : 0;

    const size_t bn = (size_t)(b * NHH + n);
    const float* Qp = Q + bn * SSS * HDD;
    const float* Kp = K + bn * SSS * HDD;
    const float* Vp = V + bn * SSS * HDD;

    float q[16];
#pragma unroll
    for (int j = 0; j < 4; ++j)
        *(float4*)&q[4 * j] = *(const float4*)(Qp + (size_t)srow * HDD + 16 * g + 4 * j);

    float acc[16];
#pragma unroll
    for (int c = 0; c < 16; ++c) acc[c] = 0.f;

    __shared__ float ks[64 * LSX];
    __shared__ float vs[64 * LSX];

    for (int tb = tb_start; tb <= qt; ++tb) {
        const int tbase = tb * 64;
        __syncthreads();
        for (int c = tid; c < 1024; c += 256) {
            int r = c >> 4, c4 = (c & 15) * 4;
            *(float4*)&ks[r * LSX + c4] = *(const float4*)(Kp + (size_t)(tbase + r) * HDD + c4);
            *(float4*)&vs[r * LSX + c4] = *(const float4*)(Vp + (size_t)(tbase + r) * HDD + c4);
        }
        __syncthreads();

        for (int t = 0; t < 64; ++t) {
            // score(srow, tbase+t): 4-thread split dot over d
            float part = 0.f;
#pragma unroll
            for (int j = 0; j < 16; ++j) part += q[j] * ks[t * LSX + 16 * g + j];
            part += __shfl_xor(part, 1);
            part += __shfl_xor(part, 2);
            int diff = srow - (tbase + t);
            float p = (diff >= 0) ? part * exp2f((float)diff * l2g) : 0.0f;
#pragma unroll
            for (int c = 0; c < 16; ++c) acc[c] += p * vs[t * LSX + 16 * g + c];
        }
    }

    // ---- fused GroupNorm over the 64 channels of this row/head ----
    float s1 = 0.f, s2 = 0.f;
#pragma unroll
    for (int c = 0; c < 16; ++c) { s1 += acc[c]; s2 += acc[c] * acc[c]; }
    s1 += __shfl_xor(s1, 1); s1 += __shfl_xor(s1, 2);
    s2 += __shfl_xor(s2, 1); s2 += __shfl_xor(s2, 2);
    float mean = s1 * (1.0f / 64.0f);
    float var  = s2 * (1.0f / 64.0f) - mean * mean;
    float rstd = 1.0f / sqrtf(var + 1e-5f);
#pragma unroll
    for (int c = 0; c < 16; ++c) {
        int ch = n * HDD + 16 * g + c;
        float nv = (acc[c] - mean) * rstd * gns[ch] + gnb[ch];
        normb[((size_t)b * SSS + srow) * HIDD + ch] = nv;
    }
}

// ---------------- plain f32 GEMM 4096x1024x1024 ----------------
// MODE 0: C' = swish(A@B) + normb, written IN-PLACE into normb
// MODE 1: out = A@B (A = normb)
template <int MODE>
__global__ __launch_bounds__(256) void k_mm_f32(const float* __restrict__ A,
                                                const float* __restrict__ Bm,
                                                float* __restrict__ normb,
                                                float* __restrict__ Out) {
    const int R0 = blockIdx.x * 64, C0 = blockIdx.y * 64;
    const int tid = threadIdx.x;
    const int row = tid >> 2, g = tid & 3;

    __shared__ float as[64 * LSX];
    __shared__ float bs[64 * LSX];

    float acc[16];
#pragma unroll
    for (int c = 0; c < 16; ++c) acc[c] = 0.f;

    for (int kk = 0; kk < HIDD / 64; ++kk) {
        __syncthreads();
        for (int c = tid; c < 1024; c += 256) {
            int r = c >> 4, c4 = (c & 15) * 4;
            *(float4*)&as[r * LSX + c4] =
                *(const float4*)(A + (size_t)(R0 + r) * HIDD + kk * 64 + c4);
            *(float4*)&bs[r * LSX + c4] =
                *(const float4*)(Bm + (size_t)(kk * 64 + r) * HIDD + C0 + c4);
        }
        __syncthreads();
        for (int d = 0; d < 64; ++d) {
            float av = as[row * LSX + d];
#pragma unroll
            for (int c = 0; c < 16; ++c) acc[c] += av * bs[d * LSX + 16 * g + c];
        }
    }

#pragma unroll
    for (int c = 0; c < 16; ++c) {
        size_t idx = (size_t)(R0 + row) * HIDD + C0 + 16 * g + c;
        if (MODE == 0) {
            float v = acc[c];
            float sw = v / (1.0f + expf(-v));
            normb[idx] = sw + normb[idx];   // y = swish(gate) + norm, in place
        } else {
            Out[idx] = acc[c];
        }
    }
}

// ------------------------------------------------------------------------------------
extern "C" void kernel_launch(void* const* d_in, const int* in_sizes, int n_in,
                              void* d_out, int out_size, void* d_ws, size_t ws_size,
                              hipStream_t stream) {
    const float* x   = (const float*)d_in[0];
    const float* wq  = (const float*)d_in[1];
    const float* wk  = (const float*)d_in[2];
    const float* wv  = (const float*)d_in[3];
    const float* w1  = (const float*)d_in[4];
    const float* w2  = (const float*)d_in[5];
    const float* gns = (const float*)d_in[6];
    const float* gnb = (const float*)d_in[7];
    float* out = (float*)d_out;

    char* base = (char*)d_ws;
    size_t off = 0;
    auto carve = [&](size_t bytes) -> void* {
        void* p = base + off;
        off += (bytes + 255) & ~(size_t)255;
        return p;
    };
    float* Q     = (float*)carve((size_t)BS * HIDD * 4);   // [B*NH][S][HD]
    float* K     = (float*)carve((size_t)BS * HIDD * 4);
    float* V     = (float*)carve((size_t)BS * HIDD * 4);
    float* normb = (float*)carve((size_t)BS * HIDD * 4);   // norm, then y in-place
    (void)ws_size; (void)in_sizes; (void)n_in; (void)out_size;

    // 1) Q/K/V projections (f32, native weight layout)
    k_proj_f32<<<dim3(BS / 64, NHH), 256, 0, stream>>>(x, wq, wk, wv, Q, K, V);
    // 2) retention + fused GroupNorm (f32)
    k_ret_f32<<<dim3(SSS / 64, NHH, BBB), 256, 0, stream>>>(Q, K, V, gns, gnb, normb);
    // 3) gate GEMM + swish + add norm (in-place into normb)
    k_mm_f32<0><<<dim3(BS / 64, HIDD / 64), 256, 0, stream>>>(x, w1, normb, nullptr);
    // 4) final GEMM -> out
    k_mm_f32<1><<<dim3(BS / 64, HIDD / 64), 256, 0, stream>>>(normb, w2, nullptr, out);
}

// Round 6
// 742.009 us; speedup vs baseline: 1.4612x; 1.4612x over previous
//
#include <hip/hip_runtime.h>

#define HIDD 1024
#define NHH  16
#define HDD  64
#define BBB  2
#define SSS  2048
#define BS   (BBB * SSS)   // 4096

#define LSX 68   // LDS row stride in f32 (64 + 4 pad)

typedef __attribute__((ext_vector_type(8))) short short8;
typedef __attribute__((ext_vector_type(4))) float f32x4;
typedef unsigned short ushort_t;

static __device__ __forceinline__ unsigned short f2b(float f) {
    union { float f; unsigned u; } v; v.f = f;
    unsigned r = v.u + 0x7FFFu + ((v.u >> 16) & 1u);
    return (unsigned short)(r >> 16);
}
static __device__ __forceinline__ float b2f(unsigned short h) {
    union { unsigned u; float f; } v; v.u = ((unsigned)h) << 16;
    return v.f;
}
static __device__ __forceinline__ f32x4 mfma16(short8 a, short8 b, f32x4 c) {
    return __builtin_amdgcn_mfma_f32_16x16x32_bf16(a, b, c, 0, 0, 0);
}

// ---------------- per-head Q/K/V projection, f32 math (VERIFIED round 3) -------------
// Outputs: Qh/Ql,Kh/Kl bf16 hi/lo [B*NH][S][HD] ; V f32 row-major [B*NH][S][HD]
__global__ __launch_bounds__(256) void k_proj_f32(const float* __restrict__ x,
                                                  const float* __restrict__ wq,
                                                  const float* __restrict__ wk,
                                                  const float* __restrict__ wv,
                                                  ushort_t* __restrict__ Qh, ushort_t* __restrict__ Ql,
                                                  ushort_t* __restrict__ Kh, ushort_t* __restrict__ Kl,
                                                  float* __restrict__ V) {
    const int n  = blockIdx.y;
    const int R0 = blockIdx.x * 64;
    const int tid = threadIdx.x;
    const int row = tid >> 2, g = tid & 3;

    __shared__ float xs[64 * LSX];
    __shared__ float ws[64 * LSX];

    for (int c = tid; c < 1024; c += 256) {
        int r = c >> 4, c4 = (c & 15) * 4;
        *(float4*)&xs[r * LSX + c4] =
            *(const float4*)(x + (size_t)(R0 + r) * HIDD + n * HDD + c4);
    }

    const float* wmats[3] = { wq, wk, wv };
    const int gr = R0 + row;
    const int b = gr >> 11, s = gr & 2047;
    const size_t bn = (size_t)(b * NHH + n);

    for (int mat = 0; mat < 3; ++mat) {
        __syncthreads();
        for (int c = tid; c < 1024; c += 256) {
            int r = c >> 4, c4 = (c & 15) * 4;
            *(float4*)&ws[r * LSX + c4] =
                *(const float4*)(wmats[mat] + (size_t)n * HDD * HDD + r * HDD + c4);
        }
        __syncthreads();

        float acc[16];
#pragma unroll
        for (int c = 0; c < 16; ++c) acc[c] = 0.f;
        for (int d = 0; d < 64; ++d) {
            float xv = xs[row * LSX + d];
#pragma unroll
            for (int c = 0; c < 16; ++c) acc[c] += xv * ws[d * LSX + 16 * g + c];
        }

        size_t idx0 = (bn * SSS + s) * HDD + 16 * g;
        if (mat == 2) {
#pragma unroll
            for (int j = 0; j < 4; ++j)
                *(float4*)(V + idx0 + 4 * j) = *(float4*)&acc[4 * j];
        } else {
#pragma unroll
            for (int c = 0; c < 16; ++c) {
                float val = acc[c];
                unsigned short vh = f2b(val);
                unsigned short vl = f2b(val - b2f(vh));
                if (mat == 0) { Qh[idx0 + c] = vh; Ql[idx0 + c] = vl; }
                else          { Kh[idx0 + c] = vh; Kl[idx0 + c] = vl; }
            }
        }
    }
}

// ------------- retention HYBRID: MFMA QK^T(+decay on C-frag)  ->  f32 LDS scores -----
// ------------- then R3-VERIFIED f32 per-thread PV + GroupNorm ------------------------
__global__ __launch_bounds__(256) void k_ret_hyb(const ushort_t* __restrict__ Qh, const ushort_t* __restrict__ Ql,
                                                 const ushort_t* __restrict__ Kh, const ushort_t* __restrict__ Kl,
                                                 const float* __restrict__ V,
                                                 const float* __restrict__ gns,
                                                 const float* __restrict__ gnb,
                                                 float* __restrict__ normb) {
    const int qt = (gridDim.x - 1) - blockIdx.x;   // heavy tiles first
    const int n = blockIdx.y, b = blockIdx.z;
    const int tid = threadIdx.x;
    const int w = tid >> 6, lane = tid & 63;
    const int hi = lane >> 4, lo = lane & 15;
    const int rloc = tid >> 2, g = tid & 3;        // R3 PV/GroupNorm decomposition

    const double l512 = -6.2383246250395075;   // log(1/512)
    const double l32  = -3.4657359027997265;   // log(1/32)
    double lin = l512 + (double)n * (l32 - l512) / 15.0;
    float gamma = (float)(1.0 - exp(lin));
    float l2g = log2f(gamma);                  // negative
    int dmax = (int)(30.0f / (-l2g)) + 1;      // keep gamma^d >= 2^-30

    const int qb = qt * 64;
    int tb_start = (qb > dmax) ? ((qb - dmax) >> 6) : 0;
    const int tb_end = qt;

    const size_t bn = (size_t)(b * NHH + n);
    const ushort_t* Qhp = Qh + bn * SSS * HDD;
    const ushort_t* Qlp = Ql + bn * SSS * HDD;
    const ushort_t* Khp = Kh + bn * SSS * HDD;
    const ushort_t* Klp = Kl + bn * SSS * HDD;
    const float*    Vp  = V  + bn * SSS * HDD;

    // Q A-fragments (split): wave w owns q rows qb+16w .. qb+16w+15
    short8 qfh[2], qfl[2];
#pragma unroll
    for (int kf = 0; kf < 2; kf++) {
        size_t o = (size_t)(qb + 16 * w + lo) * HDD + kf * 32 + 8 * hi;
        qfh[kf] = *(const short8*)(Qhp + o);
        qfl[kf] = *(const short8*)(Qlp + o);
    }

    float acc[16];
#pragma unroll
    for (int c = 0; c < 16; ++c) acc[c] = 0.f;

    __shared__ __align__(16) ushort_t ksh[64 * 72];
    __shared__ __align__(16) ushort_t ksl[64 * 72];
    __shared__ __align__(16) float vs[64 * LSX];
    __shared__ __align__(16) float sco[64 * LSX];

    for (int tb = tb_start; tb <= tb_end; ++tb) {
        const int tbase = tb * 64;
        __syncthreads();
        // stage K tile (bf16 hi/lo) and V tile (f32, row-major)
        for (int c = tid; c < 512; c += 256) {
            int r = c >> 3, j8 = (c & 7) * 8;
            *(short8*)&ksh[r * 72 + j8] = *(const short8*)(Khp + (size_t)(tbase + r) * HDD + j8);
            *(short8*)&ksl[r * 72 + j8] = *(const short8*)(Klp + (size_t)(tbase + r) * HDD + j8);
        }
        for (int c = tid; c < 1024; c += 256) {
            int r = c >> 4, c4 = (c & 15) * 4;
            *(float4*)&vs[r * LSX + c4] = *(const float4*)(Vp + (size_t)(tbase + r) * HDD + c4);
        }
        __syncthreads();

        // ---- MFMA QK^T (split ~f32) + decay applied on C-fragment -> f32 LDS ----
#pragma unroll
        for (int tt = 0; tt < 4; ++tt) {
            f32x4 sc = (f32x4){0.f, 0.f, 0.f, 0.f};
            short8 kh0 = *(const short8*)&ksh[(16 * tt + lo) * 72 + 8 * hi];
            short8 kh1 = *(const short8*)&ksh[(16 * tt + lo) * 72 + 32 + 8 * hi];
            short8 kl0 = *(const short8*)&ksl[(16 * tt + lo) * 72 + 8 * hi];
            short8 kl1 = *(const short8*)&ksl[(16 * tt + lo) * 72 + 32 + 8 * hi];
            sc = mfma16(qfh[0], kh0, sc);
            sc = mfma16(qfh[0], kl0, sc);
            sc = mfma16(qfl[0], kh0, sc);
            sc = mfma16(qfh[1], kh1, sc);
            sc = mfma16(qfh[1], kl1, sc);
            sc = mfma16(qfl[1], kh1, sc);
#pragma unroll
            for (int r = 0; r < 4; r++) {
                int qg = qb + 16 * w + 4 * hi + r;           // C row = 4*hi + r
                int tg = tbase + 16 * tt + lo;               // C col = lo
                int diff = qg - tg;
                float p = (diff >= 0) ? sc[r] * exp2f((float)diff * l2g) : 0.0f;
                sco[(16 * w + 4 * hi + r) * LSX + 16 * tt + lo] = p;
            }
        }
        __syncthreads();

        // ---- R3-VERIFIED per-thread PV accumulation (f32 VALU) ----
        for (int t = 0; t < 64; ++t) {
            float p = sco[rloc * LSX + t];
#pragma unroll
            for (int c = 0; c < 16; ++c) acc[c] += p * vs[t * LSX + 16 * g + c];
        }
    }

    // ---- R3-VERIFIED fused GroupNorm ----
    const int srow = qb + rloc;
    float s1 = 0.f, s2 = 0.f;
#pragma unroll
    for (int c = 0; c < 16; ++c) { s1 += acc[c]; s2 += acc[c] * acc[c]; }
    s1 += __shfl_xor(s1, 1); s1 += __shfl_xor(s1, 2);
    s2 += __shfl_xor(s2, 1); s2 += __shfl_xor(s2, 2);
    float mean = s1 * (1.0f / 64.0f);
    float var  = s2 * (1.0f / 64.0f) - mean * mean;
    float rstd = 1.0f / sqrtf(var + 1e-5f);
#pragma unroll
    for (int c = 0; c < 16; ++c) {
        int ch = n * HDD + 16 * g + c;
        float nv = (acc[c] - mean) * rstd * gns[ch] + gnb[ch];
        normb[((size_t)b * SSS + srow) * HIDD + ch] = nv;
    }
}

// ---------------- plain f32 GEMM (VERIFIED round 3) ----------------
template <int MODE>
__global__ __launch_bounds__(256) void k_mm_f32(const float* __restrict__ A,
                                                const float* __restrict__ Bm,
                                                float* __restrict__ normb,
                                                float* __restrict__ Out) {
    const int R0 = blockIdx.x * 64, C0 = blockIdx.y * 64;
    const int tid = threadIdx.x;
    const int row = tid >> 2, g = tid & 3;

    __shared__ float as[64 * LSX];
    __shared__ float bs[64 * LSX];

    float acc[16];
#pragma unroll
    for (int c = 0; c < 16; ++c) acc[c] = 0.f;

    for (int kk = 0; kk < HIDD / 64; ++kk) {
        __syncthreads();
        for (int c = tid; c < 1024; c += 256) {
            int r = c >> 4, c4 = (c & 15) * 4;
            *(float4*)&as[r * LSX + c4] =
                *(const float4*)(A + (size_t)(R0 + r) * HIDD + kk * 64 + c4);
            *(float4*)&bs[r * LSX + c4] =
                *(const float4*)(Bm + (size_t)(kk * 64 + r) * HIDD + C0 + c4);
        }
        __syncthreads();
        for (int d = 0; d < 64; ++d) {
            float av = as[row * LSX + d];
#pragma unroll
            for (int c = 0; c < 16; ++c) acc[c] += av * bs[d * LSX + 16 * g + c];
        }
    }

#pragma unroll
    for (int c = 0; c < 16; ++c) {
        size_t idx = (size_t)(R0 + row) * HIDD + C0 + 16 * g + c;
        if (MODE == 0) {
            float v = acc[c];
            float sw = v / (1.0f + expf(-v));
            normb[idx] = sw + normb[idx];   // y = swish(gate) + norm, in place
        } else {
            Out[idx] = acc[c];
        }
    }
}

// ------------------------------------------------------------------------------------
extern "C" void kernel_launch(void* const* d_in, const int* in_sizes, int n_in,
                              void* d_out, int out_size, void* d_ws, size_t ws_size,
                              hipStream_t stream) {
    const float* x   = (const float*)d_in[0];
    const float* wq  = (const float*)d_in[1];
    const float* wk  = (const float*)d_in[2];
    const float* wv  = (const float*)d_in[3];
    const float* w1  = (const float*)d_in[4];
    const float* w2  = (const float*)d_in[5];
    const float* gns = (const float*)d_in[6];
    const float* gnb = (const float*)d_in[7];
    float* out = (float*)d_out;

    // ---- workspace: the round-3-proven 64 MiB footprint ----
    char* base = (char*)d_ws;
    size_t off = 0;
    auto carve = [&](size_t bytes) -> void* {
        void* p = base + off;
        off += (bytes + 255) & ~(size_t)255;
        return p;
    };
    ushort_t* Qh  = (ushort_t*)carve((size_t)BS * HIDD * 2);   // 8 MiB
    ushort_t* Ql  = (ushort_t*)carve((size_t)BS * HIDD * 2);   // 8 MiB
    ushort_t* Kh  = (ushort_t*)carve((size_t)BS * HIDD * 2);   // 8 MiB
    ushort_t* Kl  = (ushort_t*)carve((size_t)BS * HIDD * 2);   // 8 MiB
    float*    V   = (float*)carve((size_t)BS * HIDD * 4);      // 16 MiB
    float*    normb = (float*)carve((size_t)BS * HIDD * 4);    // 16 MiB
    // total = 64 MiB exactly (proven safe in round 3)
    (void)ws_size; (void)in_sizes; (void)n_in; (void)out_size;

    // 1) Q/K/V projections (f32 math, verified): Q,K split bf16; V f32 row-major
    k_proj_f32<<<dim3(BS / 64, NHH), 256, 0, stream>>>(x, wq, wk, wv, Qh, Ql, Kh, Kl, V);
    // 2) retention: MFMA QK^T + decay (under test) -> f32 scores -> verified f32 PV+GN
    k_ret_hyb<<<dim3(SSS / 64, NHH, BBB), 256, 0, stream>>>(Qh, Ql, Kh, Kl, V, gns, gnb, normb);
    // 3) gate GEMM + swish + add norm (f32, verified; in-place into normb)
    k_mm_f32<0><<<dim3(BS / 64, HIDD / 64), 256, 0, stream>>>(x, w1, normb, nullptr);
    // 4) final GEMM -> out (f32, verified)
    k_mm_f32<1><<<dim3(BS / 64, HIDD / 64), 256, 0, stream>>>(normb, w2, nullptr, out);
}

// Round 8
// 712.881 us; speedup vs baseline: 1.5209x; 1.0409x over previous
//
#include <hip/hip_runtime.h>

#define HIDD 1024
#define NHH  16
#define HDD  64
#define BBB  2
#define SSS  2048
#define BS   (BBB * SSS)   // 4096

#define LSX 68   // LDS row stride in f32 (64 + 4 pad; rows stay 16B-aligned)

typedef __attribute__((ext_vector_type(8))) short short8;
typedef __attribute__((ext_vector_type(4))) float f32x4;
typedef unsigned short ushort_t;

static __device__ __forceinline__ unsigned short f2b(float f) {
    union { float f; unsigned u; } v; v.f = f;
    unsigned r = v.u + 0x7FFFu + ((v.u >> 16) & 1u);
    return (unsigned short)(r >> 16);
}
static __device__ __forceinline__ float b2f(unsigned short h) {
    union { unsigned u; float f; } v; v.u = ((unsigned)h) << 16;
    return v.f;
}
static __device__ __forceinline__ f32x4 mfma16(short8 a, short8 b, f32x4 c) {
    return __builtin_amdgcn_mfma_f32_16x16x32_bf16(a, b, c, 0, 0, 0);
}

// triple-split: v ~= h + l + ll with residual ~2^-27 |v| (each subtraction Sterbenz-exact)
static __device__ __forceinline__ void split3(float v, unsigned short& h,
                                              unsigned short& l, unsigned short& ll) {
    h = f2b(v);
    float r1 = v - b2f(h);
    l = f2b(r1);
    float r2 = r1 - b2f(l);
    ll = f2b(r2);
}

// build triple-split bf16 fragments from 8 consecutive f32 (16B-aligned)
static __device__ __forceinline__ void frag3(const float* p, short8& fh, short8& fl, short8& fll) {
    float4 a = *(const float4*)p;
    float4 b = *(const float4*)(p + 4);
    float vv[8] = { a.x, a.y, a.z, a.w, b.x, b.y, b.z, b.w };
#pragma unroll
    for (int j = 0; j < 8; ++j) {
        unsigned short h, l, ll;
        split3(vv[j], h, l, ll);
        fh[j] = (short)h; fl[j] = (short)l; fll[j] = (short)ll;
    }
}

// ---------------- per-head Q/K/V projection, f32 math (VERIFIED R3) ------------------
// Qf,Kf: [B*NH][S][HD] f32 ; VTf: [B*NH][HD][S] f32 (transposed store)
__global__ __launch_bounds__(256) void k_proj_f32(const float* __restrict__ x,
                                                  const float* __restrict__ wq,
                                                  const float* __restrict__ wk,
                                                  const float* __restrict__ wv,
                                                  float* __restrict__ Qf,
                                                  float* __restrict__ Kf,
                                                  float* __restrict__ VTf) {
    const int n  = blockIdx.y;
    const int R0 = blockIdx.x * 64;
    const int tid = threadIdx.x;
    const int row = tid >> 2, g = tid & 3;

    __shared__ float xs[64 * LSX];
    __shared__ float ws[64 * LSX];

    for (int c = tid; c < 1024; c += 256) {
        int r = c >> 4, c4 = (c & 15) * 4;
        *(float4*)&xs[r * LSX + c4] =
            *(const float4*)(x + (size_t)(R0 + r) * HIDD + n * HDD + c4);
    }

    const float* wmats[3] = { wq, wk, wv };
    const int gr = R0 + row;
    const int b = gr >> 11, s = gr & 2047;
    const size_t bn = (size_t)(b * NHH + n);

    for (int mat = 0; mat < 3; ++mat) {
        __syncthreads();
        for (int c = tid; c < 1024; c += 256) {
            int r = c >> 4, c4 = (c & 15) * 4;
            *(float4*)&ws[r * LSX + c4] =
                *(const float4*)(wmats[mat] + (size_t)n * HDD * HDD + r * HDD + c4);
        }
        __syncthreads();

        float acc[16];
#pragma unroll
        for (int c = 0; c < 16; ++c) acc[c] = 0.f;
        for (int d = 0; d < 64; ++d) {
            float xv = xs[row * LSX + d];
#pragma unroll
            for (int c = 0; c < 16; ++c) acc[c] += xv * ws[d * LSX + 16 * g + c];
        }

        if (mat == 2) {
            // transposed store: VT[bn][ch][s]
#pragma unroll
            for (int c = 0; c < 16; ++c)
                VTf[(bn * HDD + 16 * g + c) * SSS + s] = acc[c];
        } else {
            float* dst = (mat == 0) ? Qf : Kf;
            size_t basei = (bn * SSS + s) * HDD + 16 * g;
#pragma unroll
            for (int j = 0; j < 4; ++j)
                *(float4*)(dst + basei + 4 * j) = *(float4*)&acc[4 * j];
        }
    }
}

// ------ retention: R6 skeleton, triple-split MFMA QK^T and PV, f32 P round-trip ------
__global__ __launch_bounds__(256) void k_ret_mfma(const float* __restrict__ Qf,
                                                  const float* __restrict__ Kf,
                                                  const float* __restrict__ VTf,
                                                  const float* __restrict__ gns,
                                                  const float* __restrict__ gnb,
                                                  float* __restrict__ normb) {
    const int qt = (gridDim.x - 1) - blockIdx.x;   // heavy tiles first
    const int n = blockIdx.y, b = blockIdx.z;
    const int tid = threadIdx.x;
    const int w = tid >> 6, lane = tid & 63;
    const int hi = lane >> 4, lo = lane & 15;

    const double l512 = -6.2383246250395075;   // log(1/512)
    const double l32  = -3.4657359027997265;   // log(1/32)
    double lin = l512 + (double)n * (l32 - l512) / 15.0;
    float gamma = (float)(1.0 - exp(lin));
    float l2g = log2f(gamma);                  // negative
    int dmax = (int)(30.0f / (-l2g)) + 1;      // keep gamma^d >= 2^-30

    const int qb = qt * 64;
    int tb_start = (qb > dmax) ? ((qb - dmax) >> 6) : 0;
    const int tb_end = qt;

    const size_t bn = (size_t)(b * NHH + n);
    const float* Qp  = Qf  + bn * SSS * HDD;
    const float* Kp  = Kf  + bn * SSS * HDD;
    const float* VTp = VTf + bn * HDD * SSS;

    // Q fragments: triple-split in registers (row = qb+16w+lo, k-halves over d)
    short8 qfh[2], qfl[2], qfll[2];
#pragma unroll
    for (int kf = 0; kf < 2; kf++)
        frag3(Qp + (size_t)(qb + 16 * w + lo) * HDD + kf * 32 + 8 * hi,
              qfh[kf], qfl[kf], qfll[kf]);

    f32x4 acc[4];
#pragma unroll
    for (int e = 0; e < 4; e++) acc[e] = (f32x4){0.f, 0.f, 0.f, 0.f};

    __shared__ __align__(16) float ks[64 * LSX];        // K tile  [t][d]   f32
    __shared__ __align__(16) float vts[64 * LSX];       // V^T tile [ch][t] f32
    __shared__ __align__(16) float ps[4 * 16 * LSX];    // per-wave P [q16][t64] f32

    for (int tb = tb_start; tb <= tb_end; ++tb) {
        const int tbase = tb * 64;
        __syncthreads();
        for (int c = tid; c < 1024; c += 256) {
            int r = c >> 4, c4 = (c & 15) * 4;
            *(float4*)&ks[r * LSX + c4]  = *(const float4*)(Kp + (size_t)(tbase + r) * HDD + c4);
            *(float4*)&vts[r * LSX + c4] = *(const float4*)(VTp + (size_t)r * SSS + tbase + c4);
        }
        __syncthreads();

        // ---- QK^T triple-split MFMA + decay on C-frag (R6-verified indexing) ----
#pragma unroll
        for (int tt = 0; tt < 4; ++tt) {
            short8 kh[2], kl[2], kll[2];
#pragma unroll
            for (int kf = 0; kf < 2; kf++)
                frag3(&ks[(16 * tt + lo) * LSX + kf * 32 + 8 * hi], kh[kf], kl[kf], kll[kf]);
            f32x4 sc = (f32x4){0.f, 0.f, 0.f, 0.f};
#pragma unroll
            for (int kf = 0; kf < 2; kf++) {
                sc = mfma16(qfh[kf],  kh[kf],  sc);   // 1
                sc = mfma16(qfh[kf],  kl[kf],  sc);   // 2^-9
                sc = mfma16(qfl[kf],  kh[kf],  sc);   // 2^-9
                sc = mfma16(qfh[kf],  kll[kf], sc);   // 2^-18
                sc = mfma16(qfll[kf], kh[kf],  sc);   // 2^-18
                sc = mfma16(qfl[kf],  kl[kf],  sc);   // 2^-18
            }
#pragma unroll
            for (int r = 0; r < 4; r++) {
                int qg = qb + 16 * w + 4 * hi + r;
                int tg = tbase + 16 * tt + lo;
                int diff = qg - tg;
                float p = (diff >= 0) ? sc[r] * exp2f((float)diff * l2g) : 0.0f;
                ps[w * (16 * LSX) + (4 * hi + r) * LSX + 16 * tt + lo] = p;
            }
        }
        __syncthreads();

        // ---- PV triple-split MFMA (P from f32 LDS, split at read) ----
        short8 pfh[2], pfl[2], pfll[2];
#pragma unroll
        for (int kf = 0; kf < 2; kf++)
            frag3(&ps[w * (16 * LSX) + lo * LSX + kf * 32 + 8 * hi], pfh[kf], pfl[kf], pfll[kf]);
#pragma unroll
        for (int e = 0; e < 4; e++) {
            short8 vh[2], vl[2], vll[2];
#pragma unroll
            for (int kf = 0; kf < 2; kf++)
                frag3(&vts[(16 * e + lo) * LSX + kf * 32 + 8 * hi], vh[kf], vl[kf], vll[kf]);
#pragma unroll
            for (int kf = 0; kf < 2; kf++) {
                acc[e] = mfma16(pfh[kf],  vh[kf],  acc[e]);
                acc[e] = mfma16(pfh[kf],  vl[kf],  acc[e]);
                acc[e] = mfma16(pfl[kf],  vh[kf],  acc[e]);
                acc[e] = mfma16(pfh[kf],  vll[kf], acc[e]);
                acc[e] = mfma16(pfll[kf], vh[kf],  acc[e]);
                acc[e] = mfma16(pfl[kf],  vl[kf],  acc[e]);
            }
        }
    }

    // ---- fused GroupNorm on C-fragment (VERIFIED R6) ----
    float s[4], sq[4];
#pragma unroll
    for (int r = 0; r < 4; r++) {
        s[r] = 0.f; sq[r] = 0.f;
#pragma unroll
        for (int e = 0; e < 4; e++) { float v = acc[e][r]; s[r] += v; sq[r] += v * v; }
    }
#pragma unroll
    for (int mask = 1; mask < 16; mask <<= 1)
#pragma unroll
        for (int r = 0; r < 4; r++) {
            s[r]  += __shfl_xor(s[r],  mask);
            sq[r] += __shfl_xor(sq[r], mask);
        }
#pragma unroll
    for (int e = 0; e < 4; e++)
#pragma unroll
        for (int r = 0; r < 4; r++) {
            float mean = s[r] * (1.0f / 64.0f);
            float var  = sq[r] * (1.0f / 64.0f) - mean * mean;
            float rstd = rsqrtf(var + 1e-5f);
            int ch = 16 * e + lo;
            int sg = qb + 16 * w + 4 * hi + r;
            float nv = (acc[e][r] - mean) * rstd;
            nv = nv * gns[n * 64 + ch] + gnb[n * 64 + ch];
            normb[((size_t)b * SSS + sg) * HIDD + n * 64 + ch] = nv;
        }
}

// ---------------- f32 -> bf16 hi/lo ----------------
__global__ __launch_bounds__(256) void k_cvt2(const float* __restrict__ src,
                                              ushort_t* __restrict__ dh,
                                              ushort_t* __restrict__ dl) {
    int i = blockIdx.x * 256 + threadIdx.x;
    float4 v = reinterpret_cast<const float4*>(src)[i];
    ushort4 oh, ol;
    oh.x = f2b(v.x); ol.x = f2b(v.x - b2f(oh.x));
    oh.y = f2b(v.y); ol.y = f2b(v.y - b2f(oh.y));
    oh.z = f2b(v.z); ol.z = f2b(v.z - b2f(oh.z));
    oh.w = f2b(v.w); ol.w = f2b(v.w - b2f(oh.w));
    reinterpret_cast<ushort4*>(dh)[i] = oh;
    reinterpret_cast<ushort4*>(dl)[i] = ol;
}

// ------------- transpose f32 [K][N] -> bf16 hi/lo [N][K] -------------
__global__ __launch_bounds__(256) void k_tr2(const float* __restrict__ src,
                                             ushort_t* __restrict__ dh,
                                             ushort_t* __restrict__ dl,
                                             int K, int N) {
    __shared__ float ls[32][33];
    int kb = blockIdx.y * 32, nb = blockIdx.x * 32;
    int tx = threadIdx.x & 31, ty = threadIdx.x >> 5;   // 32 x 8
#pragma unroll
    for (int i = 0; i < 4; i++) {
        int r = ty + 8 * i;
        ls[r][tx] = src[(size_t)(kb + r) * N + nb + tx];
    }
    __syncthreads();
#pragma unroll
    for (int i = 0; i < 4; i++) {
        int r = ty + 8 * i;
        float v = ls[tx][r];
        unsigned short h = f2b(v);
        dh[(size_t)(nb + r) * K + kb + tx] = h;
        dl[(size_t)(nb + r) * K + kb + tx] = f2b(v - b2f(h));
    }
}

// ------- 128x128 split-bf16 MFMA GEMM (post-norm: double-split suffices) -------------
// MODE 0: v=A@B; y=swish(v)+normb; emit y hi/lo.   MODE 1: Out=A@B (f32).
template <int MODE>
__global__ __launch_bounds__(256) void k_gemm(const ushort_t* __restrict__ Ah,
                                              const ushort_t* __restrict__ Al,
                                              const ushort_t* __restrict__ Bth,
                                              const ushort_t* __restrict__ Btl,
                                              const float* __restrict__ normb,
                                              ushort_t* __restrict__ Yh,
                                              ushort_t* __restrict__ Yl,
                                              float* __restrict__ Out) {
    const int Rb = blockIdx.x * 128, Cb = blockIdx.y * 128;
    const int tid = threadIdx.x, w = tid >> 6, lane = tid & 63;
    const int hi = lane >> 4, lo = lane & 15;
    const int wm = w >> 1, wn = w & 1;

    __shared__ __align__(16) ushort_t ash[128 * 40];
    __shared__ __align__(16) ushort_t asl[128 * 40];
    __shared__ __align__(16) ushort_t bsh[128 * 40];
    __shared__ __align__(16) ushort_t bsl[128 * 40];

    f32x4 acc[4][4];
#pragma unroll
    for (int m = 0; m < 4; m++)
#pragma unroll
        for (int nn = 0; nn < 4; nn++) acc[m][nn] = (f32x4){0.f, 0.f, 0.f, 0.f};

    for (int kk = 0; kk < 32; ++kk) {
        __syncthreads();
        for (int c = tid; c < 2048; c += 256) {
            int which = c >> 9, cc = c & 511;
            int row = cc >> 2, j = cc & 3;
            size_t ga = (size_t)(Rb + row) * HIDD + kk * 32 + j * 8;
            size_t gb = (size_t)(Cb + row) * HIDD + kk * 32 + j * 8;
            if (which == 0)      *(short8*)&ash[row * 40 + j * 8] = *(const short8*)(Ah + ga);
            else if (which == 1) *(short8*)&asl[row * 40 + j * 8] = *(const short8*)(Al + ga);
            else if (which == 2) *(short8*)&bsh[row * 40 + j * 8] = *(const short8*)(Bth + gb);
            else                 *(short8*)&bsl[row * 40 + j * 8] = *(const short8*)(Btl + gb);
        }
        __syncthreads();
        short8 afh[4], afl[4], bfh[4], bfl[4];
#pragma unroll
        for (int m = 0; m < 4; m++) {
            afh[m] = *(const short8*)&ash[(64 * wm + 16 * m + lo) * 40 + 8 * hi];
            afl[m] = *(const short8*)&asl[(64 * wm + 16 * m + lo) * 40 + 8 * hi];
        }
#pragma unroll
        for (int nn = 0; nn < 4; nn++) {
            bfh[nn] = *(const short8*)&bsh[(64 * wn + 16 * nn + lo) * 40 + 8 * hi];
            bfl[nn] = *(const short8*)&bsl[(64 * wn + 16 * nn + lo) * 40 + 8 * hi];
        }
#pragma unroll
        for (int m = 0; m < 4; m++)
#pragma unroll
            for (int nn = 0; nn < 4; nn++) {
                acc[m][nn] = mfma16(afh[m], bfh[nn], acc[m][nn]);
                acc[m][nn] = mfma16(afh[m], bfl[nn], acc[m][nn]);
                acc[m][nn] = mfma16(afl[m], bfh[nn], acc[m][nn]);
            }
    }

#pragma unroll
    for (int m = 0; m < 4; m++)
#pragma unroll
        for (int nn = 0; nn < 4; nn++)
#pragma unroll
            for (int r = 0; r < 4; r++) {
                int row = Rb + 64 * wm + 16 * m + 4 * hi + r;
                int col = Cb + 64 * wn + 16 * nn + lo;
                float v = acc[m][nn][r];
                size_t idx = (size_t)row * HIDD + col;
                if (MODE == 0) {
                    float sw = v / (1.0f + expf(-v));
                    float y = sw + normb[idx];
                    unsigned short vh = f2b(y);
                    Yh[idx] = vh;
                    Yl[idx] = f2b(y - b2f(vh));
                } else {
                    Out[idx] = v;
                }
            }
}

// ------------------------------------------------------------------------------------
extern "C" void kernel_launch(void* const* d_in, const int* in_sizes, int n_in,
                              void* d_out, int out_size, void* d_ws, size_t ws_size,
                              hipStream_t stream) {
    const float* x   = (const float*)d_in[0];
    const float* wq  = (const float*)d_in[1];
    const float* wk  = (const float*)d_in[2];
    const float* wv  = (const float*)d_in[3];
    const float* w1  = (const float*)d_in[4];
    const float* w2  = (const float*)d_in[5];
    const float* gns = (const float*)d_in[6];
    const float* gnb = (const float*)d_in[7];
    float* out = (float*)d_out;

    // ---- workspace: the round-3-proven 64 MiB footprint (4 x 16 MiB f32 buffers) ----
    char* base = (char*)d_ws;
    size_t off = 0;
    auto carve = [&](size_t bytes) -> void* {
        void* p = base + off;
        off += (bytes + 255) & ~(size_t)255;
        return p;
    };
    float* Qf    = (float*)carve((size_t)BS * HIDD * 4);   // 16 MiB
    float* Kf    = (float*)carve((size_t)BS * HIDD * 4);   // 16 MiB
    float* VTf   = (float*)carve((size_t)BS * HIDD * 4);   // 16 MiB
    float* normb = (float*)carve((size_t)BS * HIDD * 4);   // 16 MiB  => 64 MiB total
    // aliases into buffers dead after k_ret:
    ushort_t* xh   = (ushort_t*)Qf;                        // 8 MiB
    ushort_t* xl   = xh + (size_t)BS * HIDD;               // 8 MiB
    ushort_t* w1th = (ushort_t*)Kf;                        // 2 MiB
    ushort_t* w1tl = w1th + (size_t)HIDD * HIDD;           // 2 MiB
    ushort_t* w2th = w1th + 2 * (size_t)HIDD * HIDD;       // 2 MiB
    ushort_t* w2tl = w1th + 3 * (size_t)HIDD * HIDD;       // 2 MiB (8 of Kf's 16)
    ushort_t* Yh   = (ushort_t*)VTf;                       // 8 MiB
    ushort_t* Yl   = Yh + (size_t)BS * HIDD;               // 8 MiB
    (void)ws_size; (void)in_sizes; (void)n_in; (void)out_size;

    // 1) projections (f32, verified): Qf,Kf row-major; VTf transposed
    k_proj_f32<<<dim3(BS / 64, NHH), 256, 0, stream>>>(x, wq, wk, wv, Qf, Kf, VTf);
    // 2) retention: triple-split MFMA QK^T + PV (f32-class accuracy), fused GroupNorm
    k_ret_mfma<<<dim3(SSS / 64, NHH, BBB), 256, 0, stream>>>(Qf, Kf, VTf, gns, gnb, normb);
    // 3) GEMM operand prep into dead buffers
    k_cvt2<<<(BS * HIDD) / 4 / 256, 256, 0, stream>>>(x, xh, xl);
    k_tr2<<<dim3(32, 32), 256, 0, stream>>>(w1, w1th, w1tl, HIDD, HIDD);
    k_tr2<<<dim3(32, 32), 256, 0, stream>>>(w2, w2th, w2tl, HIDD, HIDD);
    // 4) gate GEMM (split) + swish + add norm -> y hi/lo
    k_gemm<0><<<dim3(BS / 128, HIDD / 128), 256, 0, stream>>>(xh, xl, w1th, w1tl,
                                                              normb, Yh, Yl, nullptr);
    // 5) final GEMM (split) -> out f32
    k_gemm<1><<<dim3(BS / 128, HIDD / 128), 256, 0, stream>>>(Yh, Yl, w2th, w2tl,
                                                              nullptr, nullptr, nullptr, out);
}

// Round 9
// 362.130 us; speedup vs baseline: 2.9940x; 1.9686x over previous
//
#include <hip/hip_runtime.h>

#define HIDD 1024
#define NHH  16
#define HDD  64
#define BBB  2
#define SSS  2048
#define BS   (BBB * SSS)   // 4096

#define LSX 68   // LDS row stride in f32 (64 + 4 pad)

typedef __attribute__((ext_vector_type(8))) _Float16 half8;
typedef __attribute__((ext_vector_type(4))) _Float16 half4;
typedef __attribute__((ext_vector_type(4))) float f32x4;

#define LSCALE 2048.0f        // 2^11: pre-scale for fp16 low part
#define LINV   (1.0f / 2048.0f)

static __device__ __forceinline__ f32x4 mfma16h(half8 a, half8 b, f32x4 c) {
    return __builtin_amdgcn_mfma_f32_16x16x32_f16(a, b, c, 0, 0, 0);
}

// split2 fp16: v ~= h + l*2^-11, rep error ~2^-22 |v|
static __device__ __forceinline__ void split2h(float v, _Float16& h, _Float16& l) {
    h = (_Float16)v;
    l = (_Float16)((v - (float)h) * LSCALE);
}

// ---------------- per-head Q/K/V projection, f32 math (VERIFIED R3) ------------------
// Emits fp16 h/l: Qh/Ql,Kh/Kl [B*NH][S][HD]; VTh/VTl [B*NH][HD][S]
__global__ __launch_bounds__(256) void k_proj_f32(const float* __restrict__ x,
                                                  const float* __restrict__ wq,
                                                  const float* __restrict__ wk,
                                                  const float* __restrict__ wv,
                                                  _Float16* __restrict__ Qh, _Float16* __restrict__ Ql,
                                                  _Float16* __restrict__ Kh, _Float16* __restrict__ Kl,
                                                  _Float16* __restrict__ VTh, _Float16* __restrict__ VTl) {
    const int n  = blockIdx.y;
    const int R0 = blockIdx.x * 64;
    const int tid = threadIdx.x;
    const int row = tid >> 2, g = tid & 3;

    __shared__ float xs[64 * LSX];
    __shared__ float ws[64 * LSX];

    for (int c = tid; c < 1024; c += 256) {
        int r = c >> 4, c4 = (c & 15) * 4;
        *(float4*)&xs[r * LSX + c4] =
            *(const float4*)(x + (size_t)(R0 + r) * HIDD + n * HDD + c4);
    }

    const float* wmats[3] = { wq, wk, wv };
    const int gr = R0 + row;
    const int b = gr >> 11, s = gr & 2047;
    const size_t bn = (size_t)(b * NHH + n);

    for (int mat = 0; mat < 3; ++mat) {
        __syncthreads();
        for (int c = tid; c < 1024; c += 256) {
            int r = c >> 4, c4 = (c & 15) * 4;
            *(float4*)&ws[r * LSX + c4] =
                *(const float4*)(wmats[mat] + (size_t)n * HDD * HDD + r * HDD + c4);
        }
        __syncthreads();

        float acc[16];
#pragma unroll
        for (int c = 0; c < 16; ++c) acc[c] = 0.f;
        for (int d = 0; d < 64; ++d) {
            float xv = xs[row * LSX + d];
#pragma unroll
            for (int c = 0; c < 16; ++c) acc[c] += xv * ws[d * LSX + 16 * g + c];
        }

#pragma unroll
        for (int c = 0; c < 16; ++c) {
            int ch = 16 * g + c;
            _Float16 h, l;
            split2h(acc[c], h, l);
            if (mat == 0) {
                size_t idx = (bn * SSS + s) * HDD + ch;
                Qh[idx] = h; Ql[idx] = l;
            } else if (mat == 1) {
                size_t idx = (bn * SSS + s) * HDD + ch;
                Kh[idx] = h; Kl[idx] = l;
            } else {
                size_t idx = (bn * HDD + ch) * SSS + s;
                VTh[idx] = h; VTl[idx] = l;
            }
        }
    }
}

// -------- retention: R6/R8-verified skeleton, fp16 double-split MFMA, + GroupNorm ----
__global__ __launch_bounds__(256) void k_ret_mfma(const _Float16* __restrict__ Qh, const _Float16* __restrict__ Ql,
                                                  const _Float16* __restrict__ Kh, const _Float16* __restrict__ Kl,
                                                  const _Float16* __restrict__ VTh, const _Float16* __restrict__ VTl,
                                                  const float* __restrict__ gns,
                                                  const float* __restrict__ gnb,
                                                  float* __restrict__ normb) {
    const int qt = (gridDim.x - 1) - blockIdx.x;   // heavy tiles first
    const int n = blockIdx.y, b = blockIdx.z;
    const int tid = threadIdx.x;
    const int w = tid >> 6, lane = tid & 63;
    const int hi = lane >> 4, lo = lane & 15;

    const double l512 = -6.2383246250395075;   // log(1/512)
    const double l32  = -3.4657359027997265;   // log(1/32)
    double lin = l512 + (double)n * (l32 - l512) / 15.0;
    float gamma = (float)(1.0 - exp(lin));
    float l2g = log2f(gamma);                  // negative
    int dmax = (int)(30.0f / (-l2g)) + 1;      // keep gamma^d >= 2^-30

    const int qb = qt * 64;
    int tb_start = (qb > dmax) ? ((qb - dmax) >> 6) : 0;
    const int tb_end = qt;

    const size_t bn = (size_t)(b * NHH + n);
    const _Float16* Qhp = Qh + bn * SSS * HDD;
    const _Float16* Qlp = Ql + bn * SSS * HDD;
    const _Float16* Khp = Kh + bn * SSS * HDD;
    const _Float16* Klp = Kl + bn * SSS * HDD;
    const _Float16* Vhp = VTh + bn * HDD * SSS;
    const _Float16* Vlp = VTl + bn * HDD * SSS;

    // Q fragments (pre-split fp16, l pre-scaled 2^11)
    half8 qfh[2], qfl[2];
#pragma unroll
    for (int kf = 0; kf < 2; kf++) {
        size_t o = (size_t)(qb + 16 * w + lo) * HDD + kf * 32 + 8 * hi;
        qfh[kf] = *(const half8*)(Qhp + o);
        qfl[kf] = *(const half8*)(Qlp + o);
    }

    f32x4 acc0[4], acc1[4];
#pragma unroll
    for (int e = 0; e < 4; e++) {
        acc0[e] = (f32x4){0.f, 0.f, 0.f, 0.f};
        acc1[e] = (f32x4){0.f, 0.f, 0.f, 0.f};
    }

    __shared__ __align__(16) _Float16 ksh[64 * 72];      // K [t][d]
    __shared__ __align__(16) _Float16 ksl[64 * 72];
    __shared__ __align__(16) _Float16 vsh[64 * 72];      // V^T [ch][t]
    __shared__ __align__(16) _Float16 vsl[64 * 72];
    __shared__ __align__(16) _Float16 psh[4 * 16 * 72];  // per-wave P [q16][t64]
    __shared__ __align__(16) _Float16 psl[4 * 16 * 72];

    for (int tb = tb_start; tb <= tb_end; ++tb) {
        const int tbase = tb * 64;
        __syncthreads();
        for (int c = tid; c < 512; c += 256) {
            int r = c >> 3, j8 = (c & 7) * 8;
            *(half8*)&ksh[r * 72 + j8] = *(const half8*)(Khp + (size_t)(tbase + r) * HDD + j8);
            *(half8*)&ksl[r * 72 + j8] = *(const half8*)(Klp + (size_t)(tbase + r) * HDD + j8);
            *(half8*)&vsh[r * 72 + j8] = *(const half8*)(Vhp + (size_t)r * SSS + tbase + j8);
            *(half8*)&vsl[r * 72 + j8] = *(const half8*)(Vlp + (size_t)r * SSS + tbase + j8);
        }
        __syncthreads();

        // ---- QK^T fp16 double-split (3 MFMA / kf) + decay on C-frag (verified) ----
#pragma unroll
        for (int tt = 0; tt < 4; ++tt) {
            f32x4 s0 = (f32x4){0.f, 0.f, 0.f, 0.f};
            f32x4 s1 = (f32x4){0.f, 0.f, 0.f, 0.f};
            half8 kh0 = *(const half8*)&ksh[(16 * tt + lo) * 72 + 8 * hi];
            half8 kh1 = *(const half8*)&ksh[(16 * tt + lo) * 72 + 32 + 8 * hi];
            half8 kl0 = *(const half8*)&ksl[(16 * tt + lo) * 72 + 8 * hi];
            half8 kl1 = *(const half8*)&ksl[(16 * tt + lo) * 72 + 32 + 8 * hi];
            s0 = mfma16h(qfh[0], kh0, s0);
            s0 = mfma16h(qfh[1], kh1, s0);
            s1 = mfma16h(qfh[0], kl0, s1);
            s1 = mfma16h(qfl[0], kh0, s1);
            s1 = mfma16h(qfh[1], kl1, s1);
            s1 = mfma16h(qfl[1], kh1, s1);
#pragma unroll
            for (int r = 0; r < 4; r++) {
                int qg = qb + 16 * w + 4 * hi + r;
                int tg = tbase + 16 * tt + lo;
                int diff = qg - tg;
                float sc = s0[r] + s1[r] * LINV;
                float p = (diff >= 0) ? sc * exp2f((float)diff * l2g) : 0.0f;
                _Float16 ph, pl;
                split2h(p, ph, pl);
                int pidx = w * 1152 + (4 * hi + r) * 72 + 16 * tt + lo;
                psh[pidx] = ph;
                psl[pidx] = pl;
            }
        }
        __syncthreads();

        // ---- PV fp16 double-split MFMA ----
        half8 pfh[2], pfl[2];
#pragma unroll
        for (int kf = 0; kf < 2; kf++) {
            pfh[kf] = *(const half8*)&psh[w * 1152 + lo * 72 + kf * 32 + 8 * hi];
            pfl[kf] = *(const half8*)&psl[w * 1152 + lo * 72 + kf * 32 + 8 * hi];
        }
#pragma unroll
        for (int e = 0; e < 4; e++) {
            half8 vh0 = *(const half8*)&vsh[(16 * e + lo) * 72 + 8 * hi];
            half8 vh1 = *(const half8*)&vsh[(16 * e + lo) * 72 + 32 + 8 * hi];
            half8 vl0 = *(const half8*)&vsl[(16 * e + lo) * 72 + 8 * hi];
            half8 vl1 = *(const half8*)&vsl[(16 * e + lo) * 72 + 32 + 8 * hi];
            acc0[e] = mfma16h(pfh[0], vh0, acc0[e]);
            acc0[e] = mfma16h(pfh[1], vh1, acc0[e]);
            acc1[e] = mfma16h(pfh[0], vl0, acc1[e]);
            acc1[e] = mfma16h(pfl[0], vh0, acc1[e]);
            acc1[e] = mfma16h(pfh[1], vl1, acc1[e]);
            acc1[e] = mfma16h(pfl[1], vh1, acc1[e]);
        }
    }

    // combine scaled-low accumulator
    f32x4 accf[4];
#pragma unroll
    for (int e = 0; e < 4; e++)
#pragma unroll
        for (int r = 0; r < 4; r++)
            accf[e][r] = acc0[e][r] + acc1[e][r] * LINV;

    // ---- fused GroupNorm on C-fragment (VERIFIED R6) ----
    float s[4], sq[4];
#pragma unroll
    for (int r = 0; r < 4; r++) {
        s[r] = 0.f; sq[r] = 0.f;
#pragma unroll
        for (int e = 0; e < 4; e++) { float v = accf[e][r]; s[r] += v; sq[r] += v * v; }
    }
#pragma unroll
    for (int mask = 1; mask < 16; mask <<= 1)
#pragma unroll
        for (int r = 0; r < 4; r++) {
            s[r]  += __shfl_xor(s[r],  mask);
            sq[r] += __shfl_xor(sq[r], mask);
        }
#pragma unroll
    for (int e = 0; e < 4; e++)
#pragma unroll
        for (int r = 0; r < 4; r++) {
            float mean = s[r] * (1.0f / 64.0f);
            float var  = sq[r] * (1.0f / 64.0f) - mean * mean;
            float rstd = rsqrtf(var + 1e-5f);
            int ch = 16 * e + lo;
            int sg = qb + 16 * w + 4 * hi + r;
            float nv = (accf[e][r] - mean) * rstd;
            nv = nv * gns[n * 64 + ch] + gnb[n * 64 + ch];
            normb[((size_t)b * SSS + sg) * HIDD + n * 64 + ch] = nv;
        }
}

// ---------------- f32 -> fp16 cast ----------------
__global__ __launch_bounds__(256) void k_cvt_h(const float* __restrict__ src,
                                               _Float16* __restrict__ dst) {
    int i = blockIdx.x * 256 + threadIdx.x;
    float4 v = reinterpret_cast<const float4*>(src)[i];
    half4 o = { (_Float16)v.x, (_Float16)v.y, (_Float16)v.z, (_Float16)v.w };
    reinterpret_cast<half4*>(dst)[i] = o;
}

// ------------- transpose f32 [K][N] -> fp16 [N][K] -------------
__global__ __launch_bounds__(256) void k_tr_h(const float* __restrict__ src,
                                              _Float16* __restrict__ dst,
                                              int K, int N) {
    __shared__ float ls[32][33];
    int kb = blockIdx.y * 32, nb = blockIdx.x * 32;
    int tx = threadIdx.x & 31, ty = threadIdx.x >> 5;   // 32 x 8
#pragma unroll
    for (int i = 0; i < 4; i++) {
        int r = ty + 8 * i;
        ls[r][tx] = src[(size_t)(kb + r) * N + nb + tx];
    }
    __syncthreads();
#pragma unroll
    for (int i = 0; i < 4; i++) {
        int r = ty + 8 * i;
        dst[(size_t)(nb + r) * K + kb + tx] = (_Float16)ls[tx][r];
    }
}

// ------- 128x128 single-fp16 MFMA GEMM (post-norm: fp16 single suffices) -------------
// MODE 0: v=A@B; y=swish(v)+normb; emit y fp16.   MODE 1: Out=A@B (f32).
template <int MODE>
__global__ __launch_bounds__(256) void k_gemm_h(const _Float16* __restrict__ A,
                                                const _Float16* __restrict__ Bt,
                                                const float* __restrict__ normb,
                                                _Float16* __restrict__ Y,
                                                float* __restrict__ Out) {
    const int Rb = blockIdx.x * 128, Cb = blockIdx.y * 128;
    const int tid = threadIdx.x, w = tid >> 6, lane = tid & 63;
    const int hi = lane >> 4, lo = lane & 15;
    const int wm = w >> 1, wn = w & 1;

    __shared__ __align__(16) _Float16 as[128 * 40];
    __shared__ __align__(16) _Float16 bs[128 * 40];

    f32x4 acc[4][4];
#pragma unroll
    for (int m = 0; m < 4; m++)
#pragma unroll
        for (int nn = 0; nn < 4; nn++) acc[m][nn] = (f32x4){0.f, 0.f, 0.f, 0.f};

    for (int kk = 0; kk < 32; ++kk) {
        __syncthreads();
        for (int c = tid; c < 1024; c += 256) {
            int which = c >> 9, cc = c & 511;
            int row = cc >> 2, j = cc & 3;
            if (which == 0)
                *(half8*)&as[row * 40 + j * 8] =
                    *(const half8*)(A + (size_t)(Rb + row) * HIDD + kk * 32 + j * 8);
            else
                *(half8*)&bs[row * 40 + j * 8] =
                    *(const half8*)(Bt + (size_t)(Cb + row) * HIDD + kk * 32 + j * 8);
        }
        __syncthreads();
        half8 af[4], bf[4];
#pragma unroll
        for (int m = 0; m < 4; m++)
            af[m] = *(const half8*)&as[(64 * wm + 16 * m + lo) * 40 + 8 * hi];
#pragma unroll
        for (int nn = 0; nn < 4; nn++)
            bf[nn] = *(const half8*)&bs[(64 * wn + 16 * nn + lo) * 40 + 8 * hi];
#pragma unroll
        for (int m = 0; m < 4; m++)
#pragma unroll
            for (int nn = 0; nn < 4; nn++)
                acc[m][nn] = mfma16h(af[m], bf[nn], acc[m][nn]);
    }

#pragma unroll
    for (int m = 0; m < 4; m++)
#pragma unroll
        for (int nn = 0; nn < 4; nn++)
#pragma unroll
            for (int r = 0; r < 4; r++) {
                int row = Rb + 64 * wm + 16 * m + 4 * hi + r;
                int col = Cb + 64 * wn + 16 * nn + lo;
                float v = acc[m][nn][r];
                size_t idx = (size_t)row * HIDD + col;
                if (MODE == 0) {
                    float sw = v / (1.0f + expf(-v));
                    float y = sw + normb[idx];
                    Y[idx] = (_Float16)y;
                } else {
                    Out[idx] = v;
                }
            }
}

// ------------------------------------------------------------------------------------
extern "C" void kernel_launch(void* const* d_in, const int* in_sizes, int n_in,
                              void* d_out, int out_size, void* d_ws, size_t ws_size,
                              hipStream_t stream) {
    const float* x   = (const float*)d_in[0];
    const float* wq  = (const float*)d_in[1];
    const float* wk  = (const float*)d_in[2];
    const float* wv  = (const float*)d_in[3];
    const float* w1  = (const float*)d_in[4];
    const float* w2  = (const float*)d_in[5];
    const float* gns = (const float*)d_in[6];
    const float* gnb = (const float*)d_in[7];
    float* out = (float*)d_out;

    // ---- workspace: the proven 64 MiB footprint ----
    char* base = (char*)d_ws;
    size_t off = 0;
    auto carve = [&](size_t bytes) -> void* {
        void* p = base + off;
        off += (bytes + 255) & ~(size_t)255;
        return p;
    };
    _Float16* Qh  = (_Float16*)carve((size_t)BS * HIDD * 2);   // 8 MiB
    _Float16* Ql  = (_Float16*)carve((size_t)BS * HIDD * 2);   // 8 MiB
    _Float16* Kh  = (_Float16*)carve((size_t)BS * HIDD * 2);   // 8 MiB
    _Float16* Kl  = (_Float16*)carve((size_t)BS * HIDD * 2);   // 8 MiB
    _Float16* VTh = (_Float16*)carve((size_t)BS * HIDD * 2);   // 8 MiB
    _Float16* VTl = (_Float16*)carve((size_t)BS * HIDD * 2);   // 8 MiB
    float*    normb = (float*)carve((size_t)BS * HIDD * 4);    // 16 MiB => 64 MiB
    // aliases into buffers dead after k_ret:
    _Float16* xh  = Qh;                               // 8 MiB
    _Float16* w1t = Kh;                               // 2 MiB
    _Float16* w2t = Kh + (size_t)HIDD * HIDD;         // 2 MiB (within Kh's 8)
    _Float16* yh  = VTh;                              // 8 MiB
    (void)ws_size; (void)in_sizes; (void)n_in; (void)out_size;

    // 1) projections (f32 math, verified) -> pre-split fp16 Q/K/V^T
    k_proj_f32<<<dim3(BS / 64, NHH), 256, 0, stream>>>(x, wq, wk, wv,
                                                       Qh, Ql, Kh, Kl, VTh, VTl);
    // 2) retention: fp16 double-split MFMA QK^T + PV, fused GroupNorm
    k_ret_mfma<<<dim3(SSS / 64, NHH, BBB), 256, 0, stream>>>(Qh, Ql, Kh, Kl, VTh, VTl,
                                                             gns, gnb, normb);
    // 3) GEMM operand prep (single fp16) into dead buffers
    k_cvt_h<<<(BS * HIDD) / 4 / 256, 256, 0, stream>>>(x, xh);
    k_tr_h<<<dim3(32, 32), 256, 0, stream>>>(w1, w1t, HIDD, HIDD);
    k_tr_h<<<dim3(32, 32), 256, 0, stream>>>(w2, w2t, HIDD, HIDD);
    // 4) gate GEMM (fp16) + swish + add norm -> y fp16
    k_gemm_h<0><<<dim3(BS / 128, HIDD / 128), 256, 0, stream>>>(xh, w1t, normb, yh, nullptr);
    // 5) final GEMM (fp16) -> out f32
    k_gemm_h<1><<<dim3(BS / 128, HIDD / 128), 256, 0, stream>>>(yh, w2t, nullptr, nullptr, out);
}

// Round 10
// 278.576 us; speedup vs baseline: 3.8920x; 1.2999x over previous
//
#include <hip/hip_runtime.h>

#define HIDD 1024
#define NHH  16
#define HDD  64
#define BBB  2
#define SSS  2048
#define BS   (BBB * SSS)   // 4096

typedef __attribute__((ext_vector_type(8))) _Float16 half8;
typedef __attribute__((ext_vector_type(4))) _Float16 half4;
typedef __attribute__((ext_vector_type(4))) float f32x4;

#define LSCALE 2048.0f        // 2^11: pre-scale for fp16 low part
#define LINV   (1.0f / 2048.0f)

static __device__ __forceinline__ f32x4 mfma16h(half8 a, half8 b, f32x4 c) {
    return __builtin_amdgcn_mfma_f32_16x16x32_f16(a, b, c, 0, 0, 0);
}

// split2 fp16: v ~= h + l*2^-11, rep error ~2^-22 |v|
static __device__ __forceinline__ void split2h(float v, _Float16& h, _Float16& l) {
    h = (_Float16)v;
    l = (_Float16)((v - (float)h) * LSCALE);
}

// ---------- weight prep: W[n][d][e] f32 -> WT h/l fp16 [mat*16+n][e][d] --------------
__global__ __launch_bounds__(256) void k_wprep(const float* __restrict__ wq,
                                               const float* __restrict__ wk,
                                               const float* __restrict__ wv,
                                               _Float16* __restrict__ WTh,
                                               _Float16* __restrict__ WTl) {
    const int blk = blockIdx.x;            // mat*16 + n
    const int mat = blk >> 4, n = blk & 15;
    const float* src = (mat == 0 ? wq : mat == 1 ? wk : wv) + (size_t)n * 4096;
    for (int c = threadIdx.x; c < 4096; c += 256) {
        int e = c >> 6, d = c & 63;
        float v = src[d * 64 + e];         // reads stride-64 (L2-resident), writes coalesced
        _Float16 h, l;
        split2h(v, h, l);
        WTh[(size_t)blk * 4096 + c] = h;   // layout [e][d]
        WTl[(size_t)blk * 4096 + c] = l;
    }
}

// ---------------- per-head Q/K/V projection, fp16 double-split MFMA ------------------
// x f32; WTh/WTl pre-split. Outputs: Qh/Ql,Kh/Kl [B*NH][S][HD]; VTh/VTl [B*NH][HD][S]
__global__ __launch_bounds__(256) void k_proj_mfma(const float* __restrict__ x,
                                                   const _Float16* __restrict__ WTh,
                                                   const _Float16* __restrict__ WTl,
                                                   _Float16* __restrict__ Qh, _Float16* __restrict__ Ql,
                                                   _Float16* __restrict__ Kh, _Float16* __restrict__ Kl,
                                                   _Float16* __restrict__ VTh, _Float16* __restrict__ VTl) {
    const int n  = blockIdx.y;
    const int R0 = blockIdx.x * 64;
    const int tid = threadIdx.x;
    const int w = tid >> 6, lane = tid & 63;
    const int hi = lane >> 4, lo = lane & 15;

    __shared__ __align__(16) _Float16 wsh[64 * 72];   // WT tile [e][d], stride 72
    __shared__ __align__(16) _Float16 wsl[64 * 72];

    // A-fragments of x (row = R0+16w+lo), split once, reused for all 3 mats
    half8 ah[2], al[2];
#pragma unroll
    for (int kf = 0; kf < 2; kf++) {
        const float* xp = x + (size_t)(R0 + 16 * w + lo) * HIDD + n * HDD + kf * 32 + 8 * hi;
        float4 v0 = *(const float4*)xp;
        float4 v1 = *(const float4*)(xp + 4);
        float vv[8] = { v0.x, v0.y, v0.z, v0.w, v1.x, v1.y, v1.z, v1.w };
#pragma unroll
        for (int j = 0; j < 8; ++j) {
            _Float16 h, l;
            split2h(vv[j], h, l);
            ah[kf][j] = h; al[kf][j] = l;
        }
    }

    for (int mat = 0; mat < 3; ++mat) {
        __syncthreads();
        const _Float16* WThp = WTh + (size_t)(mat * NHH + n) * 4096;
        const _Float16* WTlp = WTl + (size_t)(mat * NHH + n) * 4096;
        for (int c = tid; c < 512; c += 256) {
            int r = c >> 3, j8 = (c & 7) * 8;
            *(half8*)&wsh[r * 72 + j8] = *(const half8*)(WThp + r * 64 + j8);
            *(half8*)&wsl[r * 72 + j8] = *(const half8*)(WTlp + r * 64 + j8);
        }
        __syncthreads();

        f32x4 a0[4], a1[4];
#pragma unroll
        for (int eb = 0; eb < 4; ++eb) {
            a0[eb] = (f32x4){0.f, 0.f, 0.f, 0.f};
            a1[eb] = (f32x4){0.f, 0.f, 0.f, 0.f};
        }
#pragma unroll
        for (int eb = 0; eb < 4; ++eb) {
            half8 bh0 = *(const half8*)&wsh[(16 * eb + lo) * 72 + 8 * hi];
            half8 bh1 = *(const half8*)&wsh[(16 * eb + lo) * 72 + 32 + 8 * hi];
            half8 bl0 = *(const half8*)&wsl[(16 * eb + lo) * 72 + 8 * hi];
            half8 bl1 = *(const half8*)&wsl[(16 * eb + lo) * 72 + 32 + 8 * hi];
            a0[eb] = mfma16h(ah[0], bh0, a0[eb]);
            a0[eb] = mfma16h(ah[1], bh1, a0[eb]);
            a1[eb] = mfma16h(ah[0], bl0, a1[eb]);
            a1[eb] = mfma16h(al[0], bh0, a1[eb]);
            a1[eb] = mfma16h(ah[1], bl1, a1[eb]);
            a1[eb] = mfma16h(al[1], bh1, a1[eb]);
        }

        if (mat < 2) {
            _Float16* Dh = (mat == 0) ? Qh : Kh;
            _Float16* Dl = (mat == 0) ? Ql : Kl;
#pragma unroll
            for (int eb = 0; eb < 4; ++eb)
#pragma unroll
                for (int r = 0; r < 4; ++r) {
                    int gr = R0 + 16 * w + 4 * hi + r;
                    int bq = gr >> 11, s = gr & 2047;
                    float val = a0[eb][r] + a1[eb][r] * LINV;
                    _Float16 h, l;
                    split2h(val, h, l);
                    size_t idx = (((size_t)(bq * NHH + n)) * SSS + s) * HDD + 16 * eb + lo;
                    Dh[idx] = h; Dl[idx] = l;
                }
        } else {
            // V: transpose via LDS (reuse wsh/wsl, stride 66), then coalesced writeout
            __syncthreads();
            _Float16* tbh = wsh;
            _Float16* tbl = wsl;
#pragma unroll
            for (int eb = 0; eb < 4; ++eb)
#pragma unroll
                for (int r = 0; r < 4; ++r) {
                    int rl = 16 * w + 4 * hi + r;
                    float val = a0[eb][r] + a1[eb][r] * LINV;
                    _Float16 h, l;
                    split2h(val, h, l);
                    tbh[rl * 66 + 16 * eb + lo] = h;
                    tbl[rl * 66 + 16 * eb + lo] = l;
                }
            __syncthreads();
            const int bq = R0 >> 11;
            const size_t bn2 = (size_t)(bq * NHH + n);
            const int sr = R0 & 2047;
            for (int c = tid; c < 4096; c += 256) {
                int ch = c >> 6, sl = c & 63;
                size_t gi = (bn2 * HDD + ch) * SSS + sr + sl;
                VTh[gi] = tbh[sl * 66 + ch];
                VTl[gi] = tbl[sl * 66 + ch];
            }
        }
    }
}

// ---- retention: 8 waves / 128 q-rows, swizzled K/V LDS, fp16 double-split MFMA ------
__global__ __launch_bounds__(512, 4) void k_ret_mfma(const _Float16* __restrict__ Qh, const _Float16* __restrict__ Ql,
                                                     const _Float16* __restrict__ Kh, const _Float16* __restrict__ Kl,
                                                     const _Float16* __restrict__ VTh, const _Float16* __restrict__ VTl,
                                                     const float* __restrict__ gns,
                                                     const float* __restrict__ gnb,
                                                     float* __restrict__ normb) {
    const int qt = (gridDim.x - 1) - blockIdx.x;   // heavy tiles first
    const int n = blockIdx.y, b = blockIdx.z;
    const int tid = threadIdx.x;
    const int w = tid >> 6, lane = tid & 63;
    const int hi = lane >> 4, lo = lane & 15;

    const double l512 = -6.2383246250395075;   // log(1/512)
    const double l32  = -3.4657359027997265;   // log(1/32)
    double lin = l512 + (double)n * (l32 - l512) / 15.0;
    float gamma = (float)(1.0 - exp(lin));
    float l2g = log2f(gamma);                  // negative
    int dmax = (int)(30.0f / (-l2g)) + 1;      // keep gamma^d >= 2^-30

    const int qb = qt * 128;
    int tb_start = (qb > dmax) ? ((qb - dmax) >> 6) : 0;
    const int tb_end = 2 * qt + 1;

    const size_t bn = (size_t)(b * NHH + n);
    const _Float16* Qhp = Qh + bn * SSS * HDD;
    const _Float16* Qlp = Ql + bn * SSS * HDD;
    const _Float16* Khp = Kh + bn * SSS * HDD;
    const _Float16* Klp = Kl + bn * SSS * HDD;
    const _Float16* Vhp = VTh + bn * HDD * SSS;
    const _Float16* Vlp = VTl + bn * HDD * SSS;

    // Q fragments (pre-split fp16)
    half8 qfh[2], qfl[2];
#pragma unroll
    for (int kf = 0; kf < 2; kf++) {
        size_t o = (size_t)(qb + 16 * w + lo) * HDD + kf * 32 + 8 * hi;
        qfh[kf] = *(const half8*)(Qhp + o);
        qfl[kf] = *(const half8*)(Qlp + o);
    }

    f32x4 acc0[4], acc1[4];
#pragma unroll
    for (int e = 0; e < 4; e++) {
        acc0[e] = (f32x4){0.f, 0.f, 0.f, 0.f};
        acc1[e] = (f32x4){0.f, 0.f, 0.f, 0.f};
    }

    // K/V tiles: linear stride 64, XOR-swizzled 16B slots (slot ^= row&7)
    __shared__ __align__(16) _Float16 ksh[64 * 64];
    __shared__ __align__(16) _Float16 ksl[64 * 64];
    __shared__ __align__(16) _Float16 vsh[64 * 64];
    __shared__ __align__(16) _Float16 vsl[64 * 64];
    __shared__ __align__(16) _Float16 psh[8 * 16 * 72];  // per-wave P [q16][t64], stride 72
    __shared__ __align__(16) _Float16 psl[8 * 16 * 72];

    const int sw0 = (hi ^ (lo & 7)) << 3;          // slot kf=0 (rows 16x+lo: row&7 == lo&7)
    const int sw1 = ((4 + hi) ^ (lo & 7)) << 3;    // slot kf=1

    for (int tb = tb_start; tb <= tb_end; ++tb) {
        const int tbase = tb * 64;
        __syncthreads();
        // stage K [t][d] and V^T [ch][t] with swizzled 16B slots
        for (int c = tid; c < 2048; c += 512) {
            int which = c >> 9, cc = c & 511, r = cc >> 3, j = cc & 7;
            int doff = r * 64 + ((j ^ (r & 7)) << 3);
            if (which == 0)      *(half8*)&ksh[doff] = *(const half8*)(Khp + (size_t)(tbase + r) * HDD + j * 8);
            else if (which == 1) *(half8*)&ksl[doff] = *(const half8*)(Klp + (size_t)(tbase + r) * HDD + j * 8);
            else if (which == 2) *(half8*)&vsh[doff] = *(const half8*)(Vhp + (size_t)r * SSS + tbase + j * 8);
            else                 *(half8*)&vsl[doff] = *(const half8*)(Vlp + (size_t)r * SSS + tbase + j * 8);
        }
        __syncthreads();

        const int qw = qb + 16 * w;
        if (tbase <= qw + 15 && tbase + 63 >= qw - dmax) {
            // ---- QK^T fp16 double-split + decay on C-frag (verified indexing) ----
#pragma unroll
            for (int tt = 0; tt < 4; ++tt) {
                int kb = (16 * tt + lo) * 64;
                half8 kh0 = *(const half8*)&ksh[kb + sw0];
                half8 kh1 = *(const half8*)&ksh[kb + sw1];
                half8 kl0 = *(const half8*)&ksl[kb + sw0];
                half8 kl1 = *(const half8*)&ksl[kb + sw1];
                f32x4 s0 = (f32x4){0.f, 0.f, 0.f, 0.f};
                f32x4 s1 = (f32x4){0.f, 0.f, 0.f, 0.f};
                s0 = mfma16h(qfh[0], kh0, s0);
                s0 = mfma16h(qfh[1], kh1, s0);
                s1 = mfma16h(qfh[0], kl0, s1);
                s1 = mfma16h(qfl[0], kh0, s1);
                s1 = mfma16h(qfh[1], kl1, s1);
                s1 = mfma16h(qfl[1], kh1, s1);
#pragma unroll
                for (int r = 0; r < 4; r++) {
                    int qg = qb + 16 * w + 4 * hi + r;
                    int tg = tbase + 16 * tt + lo;
                    int diff = qg - tg;
                    float sc = s0[r] + s1[r] * LINV;
                    float p = (diff >= 0) ? sc * exp2f((float)diff * l2g) : 0.0f;
                    _Float16 ph, pl;
                    split2h(p, ph, pl);
                    int pidx = w * 1152 + (4 * hi + r) * 72 + 16 * tt + lo;
                    psh[pidx] = ph;
                    psl[pidx] = pl;
                }
            }
            // ---- PV (per-wave P buffer: same-wave dep, no barrier needed) ----
            half8 pfh[2], pfl[2];
#pragma unroll
            for (int kf = 0; kf < 2; kf++) {
                pfh[kf] = *(const half8*)&psh[w * 1152 + lo * 72 + kf * 32 + 8 * hi];
                pfl[kf] = *(const half8*)&psl[w * 1152 + lo * 72 + kf * 32 + 8 * hi];
            }
#pragma unroll
            for (int e = 0; e < 4; e++) {
                int vb = (16 * e + lo) * 64;
                half8 vh0 = *(const half8*)&vsh[vb + sw0];
                half8 vh1 = *(const half8*)&vsh[vb + sw1];
                half8 vl0 = *(const half8*)&vsl[vb + sw0];
                half8 vl1 = *(const half8*)&vsl[vb + sw1];
                acc0[e] = mfma16h(pfh[0], vh0, acc0[e]);
                acc0[e] = mfma16h(pfh[1], vh1, acc0[e]);
                acc1[e] = mfma16h(pfh[0], vl0, acc1[e]);
                acc1[e] = mfma16h(pfl[0], vh0, acc1[e]);
                acc1[e] = mfma16h(pfh[1], vl1, acc1[e]);
                acc1[e] = mfma16h(pfl[1], vh1, acc1[e]);
            }
        }
    }

    // combine scaled-low accumulator
    f32x4 accf[4];
#pragma unroll
    for (int e = 0; e < 4; e++)
#pragma unroll
        for (int r = 0; r < 4; r++)
            accf[e][r] = acc0[e][r] + acc1[e][r] * LINV;

    // ---- fused GroupNorm on C-fragment (VERIFIED R6) ----
    float s[4], sq[4];
#pragma unroll
    for (int r = 0; r < 4; r++) {
        s[r] = 0.f; sq[r] = 0.f;
#pragma unroll
        for (int e = 0; e < 4; e++) { float v = accf[e][r]; s[r] += v; sq[r] += v * v; }
    }
#pragma unroll
    for (int mask = 1; mask < 16; mask <<= 1)
#pragma unroll
        for (int r = 0; r < 4; r++) {
            s[r]  += __shfl_xor(s[r],  mask);
            sq[r] += __shfl_xor(sq[r], mask);
        }
#pragma unroll
    for (int e = 0; e < 4; e++)
#pragma unroll
        for (int r = 0; r < 4; r++) {
            float mean = s[r] * (1.0f / 64.0f);
            float var  = sq[r] * (1.0f / 64.0f) - mean * mean;
            float rstd = rsqrtf(var + 1e-5f);
            int ch = 16 * e + lo;
            int sg = qb + 16 * w + 4 * hi + r;
            float nv = (accf[e][r] - mean) * rstd;
            nv = nv * gns[n * 64 + ch] + gnb[n * 64 + ch];
            normb[((size_t)b * SSS + sg) * HIDD + n * 64 + ch] = nv;
        }
}

// ---------------- f32 -> fp16 cast ----------------
__global__ __launch_bounds__(256) void k_cvt_h(const float* __restrict__ src,
                                               _Float16* __restrict__ dst) {
    int i = blockIdx.x * 256 + threadIdx.x;
    float4 v = reinterpret_cast<const float4*>(src)[i];
    half4 o = { (_Float16)v.x, (_Float16)v.y, (_Float16)v.z, (_Float16)v.w };
    reinterpret_cast<half4*>(dst)[i] = o;
}

// ------------- transpose f32 [K][N] -> fp16 [N][K] -------------
__global__ __launch_bounds__(256) void k_tr_h(const float* __restrict__ src,
                                              _Float16* __restrict__ dst,
                                              int K, int N) {
    __shared__ float ls[32][33];
    int kb = blockIdx.y * 32, nb = blockIdx.x * 32;
    int tx = threadIdx.x & 31, ty = threadIdx.x >> 5;   // 32 x 8
#pragma unroll
    for (int i = 0; i < 4; i++) {
        int r = ty + 8 * i;
        ls[r][tx] = src[(size_t)(kb + r) * N + nb + tx];
    }
    __syncthreads();
#pragma unroll
    for (int i = 0; i < 4; i++) {
        int r = ty + 8 * i;
        dst[(size_t)(nb + r) * K + kb + tx] = (_Float16)ls[tx][r];
    }
}

// ------- 128x128 single-fp16 MFMA GEMM (post-norm: fp16 single suffices) -------------
// MODE 0: v=A@B; y=swish(v)+normb; emit y fp16.   MODE 1: Out=A@B (f32).
template <int MODE>
__global__ __launch_bounds__(256) void k_gemm_h(const _Float16* __restrict__ A,
                                                const _Float16* __restrict__ Bt,
                                                const float* __restrict__ normb,
                                                _Float16* __restrict__ Y,
                                                float* __restrict__ Out) {
    const int Rb = blockIdx.x * 128, Cb = blockIdx.y * 128;
    const int tid = threadIdx.x, w = tid >> 6, lane = tid & 63;
    const int hi = lane >> 4, lo = lane & 15;
    const int wm = w >> 1, wn = w & 1;

    __shared__ __align__(16) _Float16 as[128 * 40];
    __shared__ __align__(16) _Float16 bs[128 * 40];

    f32x4 acc[4][4];
#pragma unroll
    for (int m = 0; m < 4; m++)
#pragma unroll
        for (int nn = 0; nn < 4; nn++) acc[m][nn] = (f32x4){0.f, 0.f, 0.f, 0.f};

    for (int kk = 0; kk < 32; ++kk) {
        __syncthreads();
        for (int c = tid; c < 1024; c += 256) {
            int which = c >> 9, cc = c & 511;
            int row = cc >> 2, j = cc & 3;
            if (which == 0)
                *(half8*)&as[row * 40 + j * 8] =
                    *(const half8*)(A + (size_t)(Rb + row) * HIDD + kk * 32 + j * 8);
            else
                *(half8*)&bs[row * 40 + j * 8] =
                    *(const half8*)(Bt + (size_t)(Cb + row) * HIDD + kk * 32 + j * 8);
        }
        __syncthreads();
        half8 af[4], bf[4];
#pragma unroll
        for (int m = 0; m < 4; m++)
            af[m] = *(const half8*)&as[(64 * wm + 16 * m + lo) * 40 + 8 * hi];
#pragma unroll
        for (int nn = 0; nn < 4; nn++)
            bf[nn] = *(const half8*)&bs[(64 * wn + 16 * nn + lo) * 40 + 8 * hi];
#pragma unroll
        for (int m = 0; m < 4; m++)
#pragma unroll
            for (int nn = 0; nn < 4; nn++)
                acc[m][nn] = mfma16h(af[m], bf[nn], acc[m][nn]);
    }

#pragma unroll
    for (int m = 0; m < 4; m++)
#pragma unroll
        for (int nn = 0; nn < 4; nn++)
#pragma unroll
            for (int r = 0; r < 4; r++) {
                int row = Rb + 64 * wm + 16 * m + 4 * hi + r;
                int col = Cb + 64 * wn + 16 * nn + lo;
                float v = acc[m][nn][r];
                size_t idx = (size_t)row * HIDD + col;
                if (MODE == 0) {
                    float sw = v / (1.0f + expf(-v));
                    float y = sw + normb[idx];
                    Y[idx] = (_Float16)y;
                } else {
                    Out[idx] = v;
                }
            }
}

// ------------------------------------------------------------------------------------
extern "C" void kernel_launch(void* const* d_in, const int* in_sizes, int n_in,
                              void* d_out, int out_size, void* d_ws, size_t ws_size,
                              hipStream_t stream) {
    const float* x   = (const float*)d_in[0];
    const float* wq  = (const float*)d_in[1];
    const float* wk  = (const float*)d_in[2];
    const float* wv  = (const float*)d_in[3];
    const float* w1  = (const float*)d_in[4];
    const float* w2  = (const float*)d_in[5];
    const float* gns = (const float*)d_in[6];
    const float* gnb = (const float*)d_in[7];
    float* out = (float*)d_out;

    // ---- workspace: the proven 64 MiB footprint ----
    char* base = (char*)d_ws;
    size_t off = 0;
    auto carve = [&](size_t bytes) -> void* {
        void* p = base + off;
        off += (bytes + 255) & ~(size_t)255;
        return p;
    };
    _Float16* Qh  = (_Float16*)carve((size_t)BS * HIDD * 2);   // 8 MiB
    _Float16* Ql  = (_Float16*)carve((size_t)BS * HIDD * 2);   // 8 MiB
    _Float16* Kh  = (_Float16*)carve((size_t)BS * HIDD * 2);   // 8 MiB
    _Float16* Kl  = (_Float16*)carve((size_t)BS * HIDD * 2);   // 8 MiB
    _Float16* VTh = (_Float16*)carve((size_t)BS * HIDD * 2);   // 8 MiB
    _Float16* VTl = (_Float16*)carve((size_t)BS * HIDD * 2);   // 8 MiB
    float*    normb = (float*)carve((size_t)BS * HIDD * 4);    // 16 MiB => 64 MiB
    // aliases:
    _Float16* WTh = (_Float16*)normb;                 // 384 KiB (dead before k_ret writes normb)
    _Float16* WTl = WTh + (size_t)48 * 4096;          // 384 KiB
    _Float16* xh  = Qh;                               // after k_ret: Q dead
    _Float16* w1t = Kh;                               // after k_ret: K dead
    _Float16* w2t = Kh + (size_t)HIDD * HIDD;
    _Float16* yh  = VTh;                              // after k_ret: VT dead
    (void)ws_size; (void)in_sizes; (void)n_in; (void)out_size;

    // 0) weight prep: transpose + pre-split wq/wk/wv into normb-aliased scratch
    k_wprep<<<48, 256, 0, stream>>>(wq, wk, wv, WTh, WTl);
    // 1) projections (fp16 double-split MFMA) -> pre-split Q/K/V^T
    k_proj_mfma<<<dim3(BS / 64, NHH), 256, 0, stream>>>(x, WTh, WTl,
                                                        Qh, Ql, Kh, Kl, VTh, VTl);
    // 2) retention: 8-wave, swizzled LDS, fp16 double-split MFMA, fused GroupNorm
    k_ret_mfma<<<dim3(SSS / 128, NHH, BBB), 512, 0, stream>>>(Qh, Ql, Kh, Kl, VTh, VTl,
                                                              gns, gnb, normb);
    // 3) GEMM operand prep (single fp16) into dead buffers
    k_cvt_h<<<(BS * HIDD) / 4 / 256, 256, 0, stream>>>(x, xh);
    k_tr_h<<<dim3(32, 32), 256, 0, stream>>>(w1, w1t, HIDD, HIDD);
    k_tr_h<<<dim3(32, 32), 256, 0, stream>>>(w2, w2t, HIDD, HIDD);
    // 4) gate GEMM (fp16) + swish + add norm -> y fp16
    k_gemm_h<0><<<dim3(BS / 128, HIDD / 128), 256, 0, stream>>>(xh, w1t, normb, yh, nullptr);
    // 5) final GEMM (fp16) -> out f32
    k_gemm_h<1><<<dim3(BS / 128, HIDD / 128), 256, 0, stream>>>(yh, w2t, nullptr, nullptr, out);
}

// Round 11
// 220.782 us; speedup vs baseline: 4.9108x; 1.2618x over previous
//
#include <hip/hip_runtime.h>

#define HIDD 1024
#define NHH  16
#define HDD  64
#define BBB  2
#define SSS  2048
#define BS   (BBB * SSS)   // 4096

typedef __attribute__((ext_vector_type(8))) _Float16 half8;
typedef __attribute__((ext_vector_type(4))) _Float16 half4;
typedef __attribute__((ext_vector_type(4))) float f32x4;

#define LSCALE 2048.0f        // 2^11: pre-scale for fp16 low part
#define LINV   (1.0f / 2048.0f)

static __device__ __forceinline__ f32x4 mfma16h(half8 a, half8 b, f32x4 c) {
    return __builtin_amdgcn_mfma_f32_16x16x32_f16(a, b, c, 0, 0, 0);
}

// split2 fp16: v ~= h + l*2^-11, rep error ~2^-22 |v|
static __device__ __forceinline__ void split2h(float v, _Float16& h, _Float16& l) {
    h = (_Float16)v;
    l = (_Float16)((v - (float)h) * LSCALE);
}

// ---------- weight prep: W[n][d][e] f32 -> WT h/l fp16 [mat*16+n][e][d] --------------
__global__ __launch_bounds__(256) void k_wprep(const float* __restrict__ wq,
                                               const float* __restrict__ wk,
                                               const float* __restrict__ wv,
                                               _Float16* __restrict__ WTh,
                                               _Float16* __restrict__ WTl) {
    const int blk = blockIdx.x;            // mat*16 + n
    const int mat = blk >> 4, n = blk & 15;
    const float* src = (mat == 0 ? wq : mat == 1 ? wk : wv) + (size_t)n * 4096;
    for (int c = threadIdx.x; c < 4096; c += 256) {
        int e = c >> 6, d = c & 63;
        float v = src[d * 64 + e];
        _Float16 h, l;
        split2h(v, h, l);
        WTh[(size_t)blk * 4096 + c] = h;   // layout [e][d]
        WTl[(size_t)blk * 4096 + c] = l;
    }
}

// ------- per-head Q/K/V projection: 8 waves/128 rows, all 3 mats staged once ---------
__global__ __launch_bounds__(512) void k_proj_mfma(const float* __restrict__ x,
                                                   const _Float16* __restrict__ WTh,
                                                   const _Float16* __restrict__ WTl,
                                                   _Float16* __restrict__ Qh, _Float16* __restrict__ Ql,
                                                   _Float16* __restrict__ Kh, _Float16* __restrict__ Kl,
                                                   _Float16* __restrict__ VTh, _Float16* __restrict__ VTl) {
    const int n  = blockIdx.y;
    const int R0 = blockIdx.x * 128;
    const int tid = threadIdx.x;
    const int w = tid >> 6, lane = tid & 63;
    const int hi = lane >> 4, lo = lane & 15;

    // 3 mats x {h,l} x [64 rows][72 stride] = 27648 halves = 54 KB
    __shared__ __align__(16) _Float16 smem[27648];

    // A-fragments of x (row = R0+16w+lo), split once, reused for all 3 mats
    half8 ah[2], al[2];
#pragma unroll
    for (int kf = 0; kf < 2; kf++) {
        const float* xp = x + (size_t)(R0 + 16 * w + lo) * HIDD + n * HDD + kf * 32 + 8 * hi;
        float4 v0 = *(const float4*)xp;
        float4 v1 = *(const float4*)(xp + 4);
        float vv[8] = { v0.x, v0.y, v0.z, v0.w, v1.x, v1.y, v1.z, v1.w };
#pragma unroll
        for (int j = 0; j < 8; ++j) {
            _Float16 h, l;
            split2h(vv[j], h, l);
            ah[kf][j] = h; al[kf][j] = l;
        }
    }

    // stage all three mats h/l (single barrier)
    for (int c = tid; c < 3072; c += 512) {
        int m = c >> 10, rest = c & 1023, hl = rest >> 9, cc = rest & 511;
        int r = cc >> 3, j8 = (cc & 7) << 3;
        const _Float16* src = (hl ? WTl : WTh) + ((size_t)(m * NHH + n)) * 4096 + r * 64 + j8;
        *(half8*)&smem[(m * 2 + hl) * 4608 + r * 72 + j8] = *(const half8*)src;
    }
    __syncthreads();

    const int bq = R0 >> 11;
    const int sr = R0 & 2047;
    const size_t bn = (size_t)(bq * NHH + n);
    float vkeep[4][4][2];   // V results live across the transpose barrier

    for (int mat = 0; mat < 3; ++mat) {
        const _Float16* bh_base = smem + (mat * 2 + 0) * 4608;
        const _Float16* bl_base = smem + (mat * 2 + 1) * 4608;
        f32x4 a0[4], a1[4];
#pragma unroll
        for (int eb = 0; eb < 4; ++eb) {
            a0[eb] = (f32x4){0.f, 0.f, 0.f, 0.f};
            a1[eb] = (f32x4){0.f, 0.f, 0.f, 0.f};
        }
#pragma unroll
        for (int eb = 0; eb < 4; ++eb) {
            half8 bh0 = *(const half8*)&bh_base[(16 * eb + lo) * 72 + 8 * hi];
            half8 bh1 = *(const half8*)&bh_base[(16 * eb + lo) * 72 + 32 + 8 * hi];
            half8 bl0 = *(const half8*)&bl_base[(16 * eb + lo) * 72 + 8 * hi];
            half8 bl1 = *(const half8*)&bl_base[(16 * eb + lo) * 72 + 32 + 8 * hi];
            a0[eb] = mfma16h(ah[0], bh0, a0[eb]);
            a0[eb] = mfma16h(ah[1], bh1, a0[eb]);
            a1[eb] = mfma16h(ah[0], bl0, a1[eb]);
            a1[eb] = mfma16h(al[0], bh0, a1[eb]);
            a1[eb] = mfma16h(ah[1], bl1, a1[eb]);
            a1[eb] = mfma16h(al[1], bh1, a1[eb]);
        }

        if (mat < 2) {
            _Float16* Dh = (mat == 0) ? Qh : Kh;
            _Float16* Dl = (mat == 0) ? Ql : Kl;
#pragma unroll
            for (int eb = 0; eb < 4; ++eb)
#pragma unroll
                for (int r = 0; r < 4; ++r) {
                    int gr = R0 + 16 * w + 4 * hi + r;
                    int s = gr & 2047;
                    float val = a0[eb][r] + a1[eb][r] * LINV;
                    _Float16 h, l;
                    split2h(val, h, l);
                    size_t idx = (bn * SSS + s) * HDD + 16 * eb + lo;
                    Dh[idx] = h; Dl[idx] = l;
                }
        } else {
#pragma unroll
            for (int eb = 0; eb < 4; ++eb)
#pragma unroll
                for (int r = 0; r < 4; ++r) {
                    vkeep[eb][r][0] = a0[eb][r];
                    vkeep[eb][r][1] = a1[eb][r];
                }
        }
    }

    // V transpose via LDS: tb[ch][rl], stride 136 (16B-aligned rows). All MFMA reads done.
    __syncthreads();
    _Float16* tbh = smem;           // 64*136 = 8704 halves
    _Float16* tbl = smem + 8704;    // ends 17408 < mat2 region (18432) — unused by now anyway
#pragma unroll
    for (int eb = 0; eb < 4; ++eb)
#pragma unroll
        for (int r = 0; r < 4; ++r) {
            int rl = 16 * w + 4 * hi + r;
            int ch = 16 * eb + lo;
            _Float16 h, l;
            split2h(vkeep[eb][r][0] + vkeep[eb][r][1] * LINV, h, l);
            tbh[ch * 136 + rl] = h;
            tbl[ch * 136 + rl] = l;
        }
    __syncthreads();
    for (int c = tid; c < 1024; c += 512) {
        int ch = c >> 4, s8 = (c & 15) << 3;
        size_t gi = (bn * HDD + ch) * SSS + sr + s8;
        *(half8*)(VTh + gi) = *(const half8*)&tbh[ch * 136 + s8];
        *(half8*)(VTl + gi) = *(const half8*)&tbl[ch * 136 + s8];
    }
}

// ---- retention: 4 waves / 64 q-rows, swizzled K/V LDS, T14 reg-prefetch staging -----
__global__ __launch_bounds__(256) void k_ret_mfma(const _Float16* __restrict__ Qh, const _Float16* __restrict__ Ql,
                                                  const _Float16* __restrict__ Kh, const _Float16* __restrict__ Kl,
                                                  const _Float16* __restrict__ VTh, const _Float16* __restrict__ VTl,
                                                  const float* __restrict__ gns,
                                                  const float* __restrict__ gnb,
                                                  float* __restrict__ normb) {
    const int qt = (gridDim.x - 1) - blockIdx.x;   // heavy tiles first
    const int n = blockIdx.y, b = blockIdx.z;
    const int tid = threadIdx.x;
    const int w = tid >> 6, lane = tid & 63;
    const int hi = lane >> 4, lo = lane & 15;

    const double l512 = -6.2383246250395075;   // log(1/512)
    const double l32  = -3.4657359027997265;   // log(1/32)
    double lin = l512 + (double)n * (l32 - l512) / 15.0;
    float gamma = (float)(1.0 - exp(lin));
    float l2g = log2f(gamma);                  // negative
    int dmax = (int)(16.0f / (-l2g)) + 1;      // keep gamma^d >= 2^-16 (mass err ~1.5e-5)

    const int qb = qt * 64;
    int tb_start = (qb > dmax) ? ((qb - dmax) >> 6) : 0;
    const int tb_end = qt;

    const size_t bn = (size_t)(b * NHH + n);
    const _Float16* Qhp = Qh + bn * SSS * HDD;
    const _Float16* Qlp = Ql + bn * SSS * HDD;
    const _Float16* Khp = Kh + bn * SSS * HDD;
    const _Float16* Klp = Kl + bn * SSS * HDD;
    const _Float16* Vhp = VTh + bn * HDD * SSS;
    const _Float16* Vlp = VTl + bn * HDD * SSS;

    // Q fragments (pre-split fp16)
    half8 qfh[2], qfl[2];
#pragma unroll
    for (int kf = 0; kf < 2; kf++) {
        size_t o = (size_t)(qb + 16 * w + lo) * HDD + kf * 32 + 8 * hi;
        qfh[kf] = *(const half8*)(Qhp + o);
        qfl[kf] = *(const half8*)(Qlp + o);
    }

    f32x4 acc0[4], acc1[4];
#pragma unroll
    for (int e = 0; e < 4; e++) {
        acc0[e] = (f32x4){0.f, 0.f, 0.f, 0.f};
        acc1[e] = (f32x4){0.f, 0.f, 0.f, 0.f};
    }

    // K/V tiles: linear stride 64, XOR-swizzled 16B slots; P: per-wave stride-72
    __shared__ __align__(16) _Float16 ksh[64 * 64];
    __shared__ __align__(16) _Float16 ksl[64 * 64];
    __shared__ __align__(16) _Float16 vsh[64 * 64];
    __shared__ __align__(16) _Float16 vsl[64 * 64];
    __shared__ __align__(16) _Float16 psh[4 * 16 * 72];
    __shared__ __align__(16) _Float16 psl[4 * 16 * 72];
    // total 50 KB -> 3 blocks/CU

    const int sw0 = (hi ^ (lo & 7)) << 3;          // slot kf=0
    const int sw1 = ((4 + hi) ^ (lo & 7)) << 3;    // slot kf=1

    half8 pre[8];   // T14 prefetch registers (8 x 16B per thread)
    auto issue = [&](int tbase) {
#pragma unroll
        for (int i = 0; i < 8; ++i) {
            int c = tid + (i << 8);
            int which = c >> 9, cc = c & 511, r = cc >> 3, j8 = (cc & 7) << 3;
            const _Float16* src =
                which == 0 ? Khp + (size_t)(tbase + r) * HDD + j8 :
                which == 1 ? Klp + (size_t)(tbase + r) * HDD + j8 :
                which == 2 ? Vhp + (size_t)r * SSS + tbase + j8 :
                             Vlp + (size_t)r * SSS + tbase + j8;
            pre[i] = *(const half8*)src;
        }
    };
    auto commit = [&]() {
#pragma unroll
        for (int i = 0; i < 8; ++i) {
            int c = tid + (i << 8);
            int which = c >> 9, cc = c & 511, r = cc >> 3, j = cc & 7;
            int doff = r * 64 + ((j ^ (r & 7)) << 3);
            _Float16* dst = which == 0 ? ksh : which == 1 ? ksl : which == 2 ? vsh : vsl;
            *(half8*)&dst[doff] = pre[i];
        }
    };

    issue(tb_start * 64);
    commit();
    __syncthreads();

    for (int tb = tb_start; tb <= tb_end; ++tb) {
        const int tbase = tb * 64;
        if (tb < tb_end) issue(tbase + 64);    // overlap next tile's loads with compute

        const int qw = qb + 16 * w;
        if (tbase <= qw + 15 && tbase + 63 >= qw - dmax) {
            // ---- QK^T fp16 double-split + decay on C-frag (verified indexing) ----
#pragma unroll
            for (int tt = 0; tt < 4; ++tt) {
                int kb = (16 * tt + lo) * 64;
                half8 kh0 = *(const half8*)&ksh[kb + sw0];
                half8 kh1 = *(const half8*)&ksh[kb + sw1];
                half8 kl0 = *(const half8*)&ksl[kb + sw0];
                half8 kl1 = *(const half8*)&ksl[kb + sw1];
                f32x4 s0 = (f32x4){0.f, 0.f, 0.f, 0.f};
                f32x4 s1 = (f32x4){0.f, 0.f, 0.f, 0.f};
                s0 = mfma16h(qfh[0], kh0, s0);
                s0 = mfma16h(qfh[1], kh1, s0);
                s1 = mfma16h(qfh[0], kl0, s1);
                s1 = mfma16h(qfl[0], kh0, s1);
                s1 = mfma16h(qfh[1], kl1, s1);
                s1 = mfma16h(qfl[1], kh1, s1);
#pragma unroll
                for (int r = 0; r < 4; r++) {
                    int qg = qb + 16 * w + 4 * hi + r;
                    int tg = tbase + 16 * tt + lo;
                    int diff = qg - tg;
                    float sc = s0[r] + s1[r] * LINV;
                    float p = (diff >= 0) ? sc * exp2f((float)diff * l2g) : 0.0f;
                    _Float16 ph, pl;
                    split2h(p, ph, pl);
                    int pidx = w * 1152 + (4 * hi + r) * 72 + 16 * tt + lo;
                    psh[pidx] = ph;
                    psl[pidx] = pl;
                }
            }
            // ---- PV (per-wave P buffer: same-wave dep, no barrier needed) ----
            half8 pfh[2], pfl[2];
#pragma unroll
            for (int kf = 0; kf < 2; kf++) {
                pfh[kf] = *(const half8*)&psh[w * 1152 + lo * 72 + kf * 32 + 8 * hi];
                pfl[kf] = *(const half8*)&psl[w * 1152 + lo * 72 + kf * 32 + 8 * hi];
            }
#pragma unroll
            for (int e = 0; e < 4; e++) {
                int vb = (16 * e + lo) * 64;
                half8 vh0 = *(const half8*)&vsh[vb + sw0];
                half8 vh1 = *(const half8*)&vsh[vb + sw1];
                half8 vl0 = *(const half8*)&vsl[vb + sw0];
                half8 vl1 = *(const half8*)&vsl[vb + sw1];
                acc0[e] = mfma16h(pfh[0], vh0, acc0[e]);
                acc0[e] = mfma16h(pfh[1], vh1, acc0[e]);
                acc1[e] = mfma16h(pfh[0], vl0, acc1[e]);
                acc1[e] = mfma16h(pfl[0], vh0, acc1[e]);
                acc1[e] = mfma16h(pfh[1], vl1, acc1[e]);
                acc1[e] = mfma16h(pfl[1], vh1, acc1[e]);
            }
        }
        __syncthreads();                 // all waves done reading current tile
        if (tb < tb_end) commit();       // write prefetched next tile
        __syncthreads();                 // staging visible before next compute
    }

    // combine scaled-low accumulator
    f32x4 accf[4];
#pragma unroll
    for (int e = 0; e < 4; e++)
#pragma unroll
        for (int r = 0; r < 4; r++)
            accf[e][r] = acc0[e][r] + acc1[e][r] * LINV;

    // ---- fused GroupNorm on C-fragment (VERIFIED R6) ----
    float s[4], sq[4];
#pragma unroll
    for (int r = 0; r < 4; r++) {
        s[r] = 0.f; sq[r] = 0.f;
#pragma unroll
        for (int e = 0; e < 4; e++) { float v = accf[e][r]; s[r] += v; sq[r] += v * v; }
    }
#pragma unroll
    for (int mask = 1; mask < 16; mask <<= 1)
#pragma unroll
        for (int r = 0; r < 4; r++) {
            s[r]  += __shfl_xor(s[r],  mask);
            sq[r] += __shfl_xor(sq[r], mask);
        }
#pragma unroll
    for (int e = 0; e < 4; e++)
#pragma unroll
        for (int r = 0; r < 4; r++) {
            float mean = s[r] * (1.0f / 64.0f);
            float var  = sq[r] * (1.0f / 64.0f) - mean * mean;
            float rstd = rsqrtf(var + 1e-5f);
            int ch = 16 * e + lo;
            int sg = qb + 16 * w + 4 * hi + r;
            float nv = (accf[e][r] - mean) * rstd;
            nv = nv * gns[n * 64 + ch] + gnb[n * 64 + ch];
            normb[((size_t)b * SSS + sg) * HIDD + n * 64 + ch] = nv;
        }
}

// ---------------- f32 -> fp16 cast ----------------
__global__ __launch_bounds__(256) void k_cvt_h(const float* __restrict__ src,
                                               _Float16* __restrict__ dst) {
    int i = blockIdx.x * 256 + threadIdx.x;
    float4 v = reinterpret_cast<const float4*>(src)[i];
    half4 o = { (_Float16)v.x, (_Float16)v.y, (_Float16)v.z, (_Float16)v.w };
    reinterpret_cast<half4*>(dst)[i] = o;
}

// ------------- transpose f32 [K][N] -> fp16 [N][K] -------------
__global__ __launch_bounds__(256) void k_tr_h(const float* __restrict__ src,
                                              _Float16* __restrict__ dst,
                                              int K, int N) {
    __shared__ float ls[32][33];
    int kb = blockIdx.y * 32, nb = blockIdx.x * 32;
    int tx = threadIdx.x & 31, ty = threadIdx.x >> 5;   // 32 x 8
#pragma unroll
    for (int i = 0; i < 4; i++) {
        int r = ty + 8 * i;
        ls[r][tx] = src[(size_t)(kb + r) * N + nb + tx];
    }
    __syncthreads();
#pragma unroll
    for (int i = 0; i < 4; i++) {
        int r = ty + 8 * i;
        dst[(size_t)(nb + r) * K + kb + tx] = (_Float16)ls[tx][r];
    }
}

// ------- 128x128 single-fp16 MFMA GEMM with T14 reg-prefetch staging -----------------
// MODE 0: v=A@B; y=swish(v)+normb; emit y fp16.   MODE 1: Out=A@B (f32).
template <int MODE>
__global__ __launch_bounds__(256) void k_gemm_h(const _Float16* __restrict__ A,
                                                const _Float16* __restrict__ Bt,
                                                const float* __restrict__ normb,
                                                _Float16* __restrict__ Y,
                                                float* __restrict__ Out) {
    const int Rb = blockIdx.x * 128, Cb = blockIdx.y * 128;
    const int tid = threadIdx.x, w = tid >> 6, lane = tid & 63;
    const int hi = lane >> 4, lo = lane & 15;
    const int wm = w >> 1, wn = w & 1;

    __shared__ __align__(16) _Float16 as[128 * 40];
    __shared__ __align__(16) _Float16 bs[128 * 40];

    f32x4 acc[4][4];
#pragma unroll
    for (int m = 0; m < 4; m++)
#pragma unroll
        for (int nn = 0; nn < 4; nn++) acc[m][nn] = (f32x4){0.f, 0.f, 0.f, 0.f};

    half8 pre[4];
    auto g_issue = [&](int kk) {
#pragma unroll
        for (int i = 0; i < 4; ++i) {
            int c = tid + (i << 8);
            int which = c >> 9, cc = c & 511, row = cc >> 2, j8 = (cc & 3) << 3;
            const _Float16* src = (which == 0)
                ? A  + (size_t)(Rb + row) * HIDD + kk * 32 + j8
                : Bt + (size_t)(Cb + row) * HIDD + kk * 32 + j8;
            pre[i] = *(const half8*)src;
        }
    };
    auto g_commit = [&]() {
#pragma unroll
        for (int i = 0; i < 4; ++i) {
            int c = tid + (i << 8);
            int which = c >> 9, cc = c & 511, row = cc >> 2, j8 = (cc & 3) << 3;
            _Float16* dst = (which == 0) ? as : bs;
            *(half8*)&dst[row * 40 + j8] = pre[i];
        }
    };

    g_issue(0);
    g_commit();
    __syncthreads();

    for (int kk = 0; kk < 32; ++kk) {
        if (kk < 31) g_issue(kk + 1);
        half8 af[4], bf[4];
#pragma unroll
        for (int m = 0; m < 4; m++)
            af[m] = *(const half8*)&as[(64 * wm + 16 * m + lo) * 40 + 8 * hi];
#pragma unroll
        for (int nn = 0; nn < 4; nn++)
            bf[nn] = *(const half8*)&bs[(64 * wn + 16 * nn + lo) * 40 + 8 * hi];
#pragma unroll
        for (int m = 0; m < 4; m++)
#pragma unroll
            for (int nn = 0; nn < 4; nn++)
                acc[m][nn] = mfma16h(af[m], bf[nn], acc[m][nn]);
        __syncthreads();
        if (kk < 31) g_commit();
        __syncthreads();
    }

#pragma unroll
    for (int m = 0; m < 4; m++)
#pragma unroll
        for (int nn = 0; nn < 4; nn++)
#pragma unroll
            for (int r = 0; r < 4; r++) {
                int row = Rb + 64 * wm + 16 * m + 4 * hi + r;
                int col = Cb + 64 * wn + 16 * nn + lo;
                float v = acc[m][nn][r];
                size_t idx = (size_t)row * HIDD + col;
                if (MODE == 0) {
                    float sw = v / (1.0f + expf(-v));
                    float y = sw + normb[idx];
                    Y[idx] = (_Float16)y;
                } else {
                    Out[idx] = v;
                }
            }
}

// ------------------------------------------------------------------------------------
extern "C" void kernel_launch(void* const* d_in, const int* in_sizes, int n_in,
                              void* d_out, int out_size, void* d_ws, size_t ws_size,
                              hipStream_t stream) {
    const float* x   = (const float*)d_in[0];
    const float* wq  = (const float*)d_in[1];
    const float* wk  = (const float*)d_in[2];
    const float* wv  = (const float*)d_in[3];
    const float* w1  = (const float*)d_in[4];
    const float* w2  = (const float*)d_in[5];
    const float* gns = (const float*)d_in[6];
    const float* gnb = (const float*)d_in[7];
    float* out = (float*)d_out;

    // ---- workspace: the proven 64 MiB footprint ----
    char* base = (char*)d_ws;
    size_t off = 0;
    auto carve = [&](size_t bytes) -> void* {
        void* p = base + off;
        off += (bytes + 255) & ~(size_t)255;
        return p;
    };
    _Float16* Qh  = (_Float16*)carve((size_t)BS * HIDD * 2);   // 8 MiB
    _Float16* Ql  = (_Float16*)carve((size_t)BS * HIDD * 2);   // 8 MiB
    _Float16* Kh  = (_Float16*)carve((size_t)BS * HIDD * 2);   // 8 MiB
    _Float16* Kl  = (_Float16*)carve((size_t)BS * HIDD * 2);   // 8 MiB
    _Float16* VTh = (_Float16*)carve((size_t)BS * HIDD * 2);   // 8 MiB
    _Float16* VTl = (_Float16*)carve((size_t)BS * HIDD * 2);   // 8 MiB
    float*    normb = (float*)carve((size_t)BS * HIDD * 4);    // 16 MiB => 64 MiB
    // aliases:
    _Float16* WTh = (_Float16*)normb;                 // 384 KiB (normb written later by k_ret)
    _Float16* WTl = WTh + (size_t)48 * 4096;          // 384 KiB
    _Float16* xh  = Qh;                               // after k_ret: Q dead
    _Float16* w1t = Kh;                               // after k_ret: K dead
    _Float16* w2t = Kh + (size_t)HIDD * HIDD;
    _Float16* yh  = VTh;                              // after k_ret: VT dead
    (void)ws_size; (void)in_sizes; (void)n_in; (void)out_size;

    // 0) weight prep: transpose + pre-split wq/wk/wv
    k_wprep<<<48, 256, 0, stream>>>(wq, wk, wv, WTh, WTl);
    // 1) projections (fp16 double-split MFMA, single-stage weights) -> Q/K/V^T
    k_proj_mfma<<<dim3(BS / 128, NHH), 512, 0, stream>>>(x, WTh, WTl,
                                                         Qh, Ql, Kh, Kl, VTh, VTl);
    // 2) retention: 4-wave blocks, swizzled LDS, reg-prefetch, fused GroupNorm
    k_ret_mfma<<<dim3(SSS / 64, NHH, BBB), 256, 0, stream>>>(Qh, Ql, Kh, Kl, VTh, VTl,
                                                             gns, gnb, normb);
    // 3) GEMM operand prep (single fp16) into dead buffers
    k_cvt_h<<<(BS * HIDD) / 4 / 256, 256, 0, stream>>>(x, xh);
    k_tr_h<<<dim3(32, 32), 256, 0, stream>>>(w1, w1t, HIDD, HIDD);
    k_tr_h<<<dim3(32, 32), 256, 0, stream>>>(w2, w2t, HIDD, HIDD);
    // 4) gate GEMM (fp16) + swish + add norm -> y fp16
    k_gemm_h<0><<<dim3(BS / 128, HIDD / 128), 256, 0, stream>>>(xh, w1t, normb, yh, nullptr);
    // 5) final GEMM (fp16) -> out f32
    k_gemm_h<1><<<dim3(BS / 128, HIDD / 128), 256, 0, stream>>>(yh, w2t, nullptr, nullptr, out);
}